// Round 6
// baseline (37779.922 us; speedup 1.0000x reference)
//
#include <hip/hip_runtime.h>
#include <hip/hip_bf16.h>

#define T_LEN 4096
#define HID   512
#define EMB   256
#define KTAG  16
#define START_TAG 14
#define END_TAG   15
#define NEGV  (-10000.0f)
#define NTEAM   32   // elected team: 16 WGs per direction
#define NLAUNCH 256  // 1 block/CU; argmax XCD holds >= 32 by pigeonhole

// elect[] int indices
#define E_CENSUS 0   // 0..7
#define E_ARRIVE 8
#define E_CHOSEN 9
#define E_CLAIM  10
#define E_VOTE   12
#define E_XCC    16  // 16..47: per-slot xcc+1

__device__ __forceinline__ unsigned long long packph(float h, unsigned tag) {
  return ((unsigned long long)tag << 32) | (unsigned long long)__float_as_uint(h);
}

// ---- FAST protocol: everything executes AT the XCD L2 via atomics ----
// publish: 64b atomic swap, no return -> prompt L2 execution, never WC-lazy
__device__ __forceinline__ void pub_fast(unsigned long long* p, unsigned long long v) {
  asm volatile("global_atomic_swap_x2 %0, %1, off" :: "v"(p), "v"(v) : "memory");
}
// poll: two 64b atomic add-0 with return (sc0) -> guaranteed-fresh L2 reads
__device__ __forceinline__ void poll2_issue(const unsigned long long* p,
                                            unsigned long long& r0,
                                            unsigned long long& r1,
                                            unsigned long long z) {
  asm volatile("global_atomic_add_x2 %0, %2, %4, off sc0\n\t"
               "global_atomic_add_x2 %1, %3, %4, off sc0"
               : "=&v"(r0), "=&v"(r1)
               : "v"(p), "v"(p + 1), "v"(z) : "memory");
}
__device__ __forceinline__ void poll2_wait(unsigned long long& r0,
                                           unsigned long long& r1) {
  asm volatile("s_waitcnt vmcnt(0)" : "+v"(r0), "+v"(r1) :: "memory");
}
// ---- agent-scope ops (round-3 proven fallback) ----
__device__ __forceinline__ unsigned long long ld_pair_agent(const unsigned long long* p) {
  return __hip_atomic_load(p, __ATOMIC_RELAXED, __HIP_MEMORY_SCOPE_AGENT);
}
__device__ __forceinline__ void st_pair_agent(unsigned long long* p, unsigned long long v) {
  __hip_atomic_store(p, v, __ATOMIC_RELAXED, __HIP_MEMORY_SCOPE_AGENT);
}

// ---------------------------------------------------------------------------
// Main recurrence body. Team of 32 WGs; WG slot s: dir=s>>4, owns comps
// [32*(s&15), +32). Wave w = k-quarter; lane l handles rows (gate=l>>4,
// j=(l&15)) and (gate, (l&15)+16): 384 weight f32 in registers. Per step:
// poll own 128-comp chunk (2 tagged pairs/lane) -> LDS -> FMA -> one
// __syncthreads -> wave0 reduce/activation -> publish 32-pair burst.
// ---------------------------------------------------------------------------
template<int FAST>
__device__ void lstm_body(
    const float* __restrict__ Whh, const float* __restrict__ Wih,
    const float* __restrict__ bb,  const float* __restrict__ c0,
    const int*   __restrict__ x,   const float* __restrict__ embed,
    unsigned long long* __restrict__ pb, float* __restrict__ hOut,
    int dir, int sl, int w, int l)
{
  const int J0   = sl * 32;
  const int jl   = l & 15;
  const int gate = l >> 4;
  const int r0   = gate * HID + J0 + jl;
  const int r1   = r0 + 16;

  float wh0[128], wh1[128], we0[64], we1[64];
  {
    const float* p0 = Whh + (size_t)r0 * HID + w * 128;
    const float* p1 = Whh + (size_t)r1 * HID + w * 128;
    #pragma unroll
    for (int i = 0; i < 32; ++i) {
      *(float4*)&wh0[i*4] = *(const float4*)&p0[i*4];
      *(float4*)&wh1[i*4] = *(const float4*)&p1[i*4];
    }
    const float* q0 = Wih + (size_t)r0 * EMB + w * 64;
    const float* q1 = Wih + (size_t)r1 * EMB + w * 64;
    #pragma unroll
    for (int i = 0; i < 16; ++i) {
      *(float4*)&we0[i*4] = *(const float4*)&q0[i*4];
      *(float4*)&we1[i*4] = *(const float4*)&q1[i*4];
    }
  }
  // activation-lane constants (wave0 lanes 0..31 use them)
  const int ac = J0 + (l & 31);
  const float bi = bb[ac], bfg = bb[HID + ac];
  const float bg = bb[2*HID + ac], bo = bb[3*HID + ac];
  float cst = c0[dir * HID + ac];

  __shared__ float hl[4][128];
  __shared__ float el[4][64];
  __shared__ float ps[2][4][2][64];

  // prefetch emb quarter for step 0
  float epf;
  {
    const int tt0 = dir ? (T_LEN - 1) : 0;
    epf = embed[(size_t)x[tt0] * EMB + w * 64 + l];
  }

  unsigned spins = 0;
  const unsigned long long zz = 0;

  for (int t = 0; t < T_LEN; ++t) {
    const int par = t & 1;
    const int tt  = dir ? (T_LEN - 1 - t) : t;

    // issue this wave's 2-pair poll early (in flight during emb work)
    unsigned long long* psrc = pb + ((par ^ 1) * 512) + w * 128 + 2 * l;
    unsigned long long sp0 = 0, sp1 = 0;
    if (FAST) {
      poll2_issue(psrc, sp0, sp1, zz);
    } else {
      sp0 = ld_pair_agent(&psrc[0]);
      sp1 = ld_pair_agent(&psrc[1]);
    }

    // stage emb quarter (intra-wave only)
    el[w][l] = epf;
    __builtin_amdgcn_wave_barrier();
    asm volatile("s_waitcnt lgkmcnt(0)" ::: "memory");
    __builtin_amdgcn_sched_barrier(0);

    // emb contribution overlaps the poll latency (chain order == round 3)
    float acc0 = 0.f, acc1 = 0.f;
    {
      const float* eseg = el[w];
      #pragma unroll
      for (int i = 0; i < 16; ++i) {
        float4 ev = *(const float4*)&eseg[i*4];
        acc0 += we0[i*4+0]*ev.x + we0[i*4+1]*ev.y + we0[i*4+2]*ev.z + we0[i*4+3]*ev.w;
        acc1 += we1[i*4+0]*ev.x + we1[i*4+1]*ev.y + we1[i*4+2]*ev.z + we1[i*4+3]*ev.w;
      }
    }

    // spin until this wave's chunk carries tag t+1 (h_{t-1})
    const unsigned tgt = (unsigned)(t + 1);
    if (FAST) {
      poll2_wait(sp0, sp1);
      for (;;) {
        const bool f = ((unsigned)(sp0 >> 32) == tgt) && ((unsigned)(sp1 >> 32) == tgt);
        if (__all(f)) break;
        if (++spins > 2000000u) break;   // safety valve
        poll2_issue(psrc, sp0, sp1, zz);
        poll2_wait(sp0, sp1);
      }
    } else {
      for (;;) {
        const bool f = ((unsigned)(sp0 >> 32) == tgt) && ((unsigned)(sp1 >> 32) == tgt);
        if (__all(f)) break;
        if (++spins > 2000000u) break;
        __builtin_amdgcn_s_sleep(1);
        sp0 = ld_pair_agent(&psrc[0]);
        sp1 = ld_pair_agent(&psrc[1]);
      }
    }

    // polled chunk -> per-wave LDS
    {
      float2 hv2;
      hv2.x = __uint_as_float((unsigned)sp0);
      hv2.y = __uint_as_float((unsigned)sp1);
      *(float2*)&hl[w][2*l] = hv2;
    }
    __builtin_amdgcn_wave_barrier();
    asm volatile("s_waitcnt lgkmcnt(0)" ::: "memory");
    __builtin_amdgcn_sched_barrier(0);

    // h contribution (same-address quads broadcast, conflict-free)
    {
      const float* hseg = hl[w];
      #pragma unroll
      for (int i = 0; i < 32; ++i) {
        float4 hv = *(const float4*)&hseg[i*4];
        acc0 += wh0[i*4+0]*hv.x + wh0[i*4+1]*hv.y + wh0[i*4+2]*hv.z + wh0[i*4+3]*hv.w;
        acc1 += wh1[i*4+0]*hv.x + wh1[i*4+1]*hv.y + wh1[i*4+2]*hv.z + wh1[i*4+3]*hv.w;
      }
    }

    ps[par][w][0][l] = acc0;
    ps[par][w][1][l] = acc1;
    __syncthreads();   // the one per-step intra-WG join

    if (w == 0) {
      const float t0 = (ps[par][0][0][l] + ps[par][1][0][l])
                     + (ps[par][2][0][l] + ps[par][3][0][l]);   // round-3 tree
      const float t1 = (ps[par][0][1][l] + ps[par][1][1][l])
                     + (ps[par][2][1][l] + ps[par][3][1][l]);
      const float a0 = __shfl(t0, jl),      b0 = __shfl(t1, jl);
      const float a1 = __shfl(t0, 16 + jl), b1 = __shfl(t1, 16 + jl);
      const float a2 = __shfl(t0, 32 + jl), b2 = __shfl(t1, 32 + jl);
      const float a3 = __shfl(t0, 48 + jl), b3 = __shfl(t1, 48 + jl);
      if (l < 32) {
        const bool hi = (l & 16) != 0;
        const float gi_ = (hi ? b0 : a0) + bi;
        const float gf_ = (hi ? b1 : a1) + bfg;
        const float gg_ = (hi ? b2 : a2) + bg;
        const float go_ = (hi ? b3 : a3) + bo;
        const float si = 1.f / (1.f + expf(-gi_));
        const float sf = 1.f / (1.f + expf(-gf_));
        const float so = 1.f / (1.f + expf(-go_));
        const float cn = sf * cst + si * tanhf(gg_);
        cst = cn;
        const float hv = so * tanhf(cn);
        const unsigned long long pk = packph(hv, (unsigned)(t + 2));
        if (FAST) pub_fast(&pb[par * 512 + J0 + l], pk);
        else      st_pair_agent(&pb[par * 512 + J0 + l], pk);
        hOut[((size_t)dir * T_LEN + tt) * HID + J0 + l] = hv;
      }
    }

    // prefetch next emb quarter (hides under next step's poll)
    if (t + 1 < T_LEN) {
      const int ttn = dir ? (T_LEN - 2 - t) : (t + 1);
      epf = embed[(size_t)x[ttn] * EMB + w * 64 + l];
    }
  }
}

// ---------------------------------------------------------------------------
// Election + verified-fast / agent-fallback dispatcher. All spins bounded;
// correctness never depends on placement, XCC_ID truth, or atomic routing:
// the handshake exercises the exact main-loop pattern and votes.
// ---------------------------------------------------------------------------
__global__ __launch_bounds__(256, 1) void lstm_kernel(
    const float* __restrict__ Whh_f, const float* __restrict__ Whh_b,
    const float* __restrict__ Wih_f, const float* __restrict__ Wih_b,
    const float* __restrict__ b_f,  const float* __restrict__ b_b,
    const float* __restrict__ h0,   const float* __restrict__ c0,
    const int*   __restrict__ x,    const float* __restrict__ embed,
    unsigned long long* __restrict__ pairs,    // fast-mode pair buffer
    unsigned long long* __restrict__ pairs2,   // agent-mode pair buffer
    float* __restrict__ hOut, int* __restrict__ elect)
{
  const int tid = threadIdx.x;
  __shared__ int s_slot, s_mode;
  __shared__ int s_ok[4];

  // ---- phase 1: census + choose + claim (tid 0) ----
  if (tid == 0) {
    int xcc;
    asm volatile("s_getreg_b32 %0, hwreg(HW_REG_XCC_ID)" : "=s"(xcc));
    xcc &= 7;
    __hip_atomic_fetch_add(&elect[E_CENSUS + xcc], 1, __ATOMIC_RELAXED, __HIP_MEMORY_SCOPE_AGENT);
    const int a = __hip_atomic_fetch_add(&elect[E_ARRIVE], 1, __ATOMIC_ACQ_REL, __HIP_MEMORY_SCOPE_AGENT);
    if (a == NLAUNCH - 1) {
      int best = 0, bc = -1;
      for (int i = 0; i < 8; ++i) {
        const int ci = __hip_atomic_load(&elect[E_CENSUS + i], __ATOMIC_RELAXED, __HIP_MEMORY_SCOPE_AGENT);
        if (ci > bc) { bc = ci; best = i; }
      }
      __hip_atomic_store(&elect[E_CHOSEN], best + 1, __ATOMIC_RELEASE, __HIP_MEMORY_SCOPE_AGENT);
    }
    int ch = 0;
    for (unsigned g = 0; g < 300000u; ++g) {
      ch = __hip_atomic_load(&elect[E_CHOSEN], __ATOMIC_ACQUIRE, __HIP_MEMORY_SCOPE_AGENT);
      if (ch) break;
      __builtin_amdgcn_s_sleep(2);
    }
    int slot = -1;
    if (ch == 0 || ch - 1 == xcc) {    // ch==0: degraded, claim anyway (agent mode will win)
      const int cl = __hip_atomic_fetch_add(&elect[E_CLAIM], 1, __ATOMIC_RELAXED, __HIP_MEMORY_SCOPE_AGENT);
      if (cl < NTEAM) slot = cl;
    }
    if (slot >= 0)
      __hip_atomic_store(&elect[E_XCC + slot], xcc + 1, __ATOMIC_RELEASE, __HIP_MEMORY_SCOPE_AGENT);
    s_slot = slot;
  }
  __syncthreads();
  const int slot = s_slot;
  if (slot < 0) return;   // not on the team

  const int dir = slot >> 4;
  const int sl  = slot & 15;
  const int J0  = sl * 32;
  const int w   = tid >> 6;
  const int l   = tid & 63;

  // ---- phase 2: membership + XCC uniformity (provisional mode) ----
  if (tid == 0) {
    int uni = 0;
    for (unsigned g = 0; g < 60000u; ++g) {
      int allnz = 1;
      for (int i = 0; i < NTEAM; ++i)
        if (!__hip_atomic_load(&elect[E_XCC + i], __ATOMIC_ACQUIRE, __HIP_MEMORY_SCOPE_AGENT)) { allnz = 0; break; }
      if (allnz) { uni = 1; break; }
      __builtin_amdgcn_s_sleep(2);
    }
    if (uni) {
      const int v0 = __hip_atomic_load(&elect[E_XCC], __ATOMIC_RELAXED, __HIP_MEMORY_SCOPE_AGENT);
      for (int i = 1; i < NTEAM; ++i)
        if (__hip_atomic_load(&elect[E_XCC + i], __ATOMIC_RELAXED, __HIP_MEMORY_SCOPE_AGENT) != v0) { uni = 0; break; }
    }
    s_mode = uni;
  }
  __syncthreads();

  // ---- phase 3: atomic handshake (exact main-loop access pattern) + vote ----
  if (s_mode) {
    if (w == 0 && l < 32)
      pub_fast(&pairs[(size_t)dir * 1024 + 512 + J0 + l],
               packph(h0[dir * HID + J0 + l], 1u));
    int okw = 0;
    {
      const unsigned long long* hp = pairs + (size_t)dir * 1024 + 512 + w * 128 + 2 * l;
      unsigned long long r0, r1; const unsigned long long zz = 0;
      for (unsigned g = 0; g < 20000u; ++g) {
        poll2_issue(hp, r0, r1, zz);
        poll2_wait(r0, r1);
        if (__all(((unsigned)(r0 >> 32) == 1u) && ((unsigned)(r1 >> 32) == 1u))) { okw = 1; break; }
      }
    }
    if (l == 0) s_ok[w] = okw;
    __syncthreads();
    if (tid == 0) {
      const int ok = s_ok[0] & s_ok[1] & s_ok[2] & s_ok[3];
      __hip_atomic_fetch_add(&elect[E_VOTE], ok ? 1 : 0x10000, __ATOMIC_ACQ_REL, __HIP_MEMORY_SCOPE_AGENT);
      int v = 0;
      for (unsigned g = 0; g < 300000u; ++g) {
        v = __hip_atomic_load(&elect[E_VOTE], __ATOMIC_ACQUIRE, __HIP_MEMORY_SCOPE_AGENT);
        if ((v & 0xffff) + (v >> 16) >= NTEAM) break;
        __builtin_amdgcn_s_sleep(2);
      }
      s_mode = ((v >> 16) == 0 && (v & 0xffff) >= NTEAM) ? 1 : 0;
    }
    __syncthreads();
  }
  const int mode = s_mode;

  if (!mode) {   // agent fallback: fresh buffer, republish h_{-1}
    if (w == 0 && l < 32)
      st_pair_agent(&pairs2[(size_t)dir * 1024 + 512 + J0 + l],
                    packph(h0[dir * HID + J0 + l], 1u));
  }

  const float* Whh = dir ? Whh_b : Whh_f;
  const float* Wih = dir ? Wih_b : Wih_f;
  const float* bb  = dir ? b_b  : b_f;

  if (mode)
    lstm_body<1>(Whh, Wih, bb, c0, x, embed, pairs  + (size_t)dir * 1024, hOut, dir, sl, w, l);
  else
    lstm_body<0>(Whh, Wih, bb, c0, x, embed, pairs2 + (size_t)dir * 1024, hOut, dir, sl, w, l);
}

// ---------------------------------------------------------------------------
// feats[t][k] = concat(hf[t], hb[t]) . fc_w[k] + fc_b[k]
// ---------------------------------------------------------------------------
__global__ __launch_bounds__(256) void feats_kernel(
    const float* __restrict__ hOut, const float* __restrict__ fc_w,
    const float* __restrict__ fc_b, float* __restrict__ feats)
{
  const int tid = threadIdx.x;
  const int k   = tid & 15;
  const int tl  = tid >> 4;
  const int t   = blockIdx.x * 16 + tl;
  const float* hf = hOut + (size_t)t * HID;
  const float* hb = hOut + ((size_t)T_LEN + t) * HID;
  const float* wr = fc_w + (size_t)k * (2 * HID);
  float acc = fc_b[k];
  #pragma unroll 4
  for (int j = 0; j < HID; j += 4) {
    float4 hv = *(const float4*)&hf[j];
    float4 wv = *(const float4*)&wr[j];
    acc += hv.x*wv.x + hv.y*wv.y + hv.z*wv.z + hv.w*wv.w;
  }
  #pragma unroll 4
  for (int j = 0; j < HID; j += 4) {
    float4 hv = *(const float4*)&hb[j];
    float4 wv = *(const float4*)&wr[HID + j];
    acc += hv.x*wv.x + hv.y*wv.y + hv.z*wv.z + hv.w*wv.w;
  }
  feats[(size_t)t * KTAG + k] = acc;
}

// ---------------------------------------------------------------------------
// Viterbi: single block. DP state vl kept in wave-0 REGISTERS (lane 4n holds
// vl[n]); gathers via __shfl — no per-step LDS round trip. First-max tie
// rules preserved exactly. Backtrack via per-64-step chunk maps.
// ---------------------------------------------------------------------------
__global__ __launch_bounds__(256) void viterbi_kernel(
    const float* __restrict__ feats, const float* __restrict__ trans,
    float* __restrict__ out)
{
  __shared__ float fch[256 * KTAG];           // 16 KB feats chunk
  __shared__ unsigned char bps8[T_LEN * 8];   // 32 KB packed backpointers
  __shared__ unsigned char ml[64 * 16];       // chunk maps
  __shared__ unsigned char rb[64];            // chunk right-boundary tags
  __shared__ int sbest;

  const int tid  = threadIdx.x;
  const int lane = tid & 63;
  const int nxt  = lane >> 2;
  const int pg   = lane & 3;

  float tr[4] = {0.f, 0.f, 0.f, 0.f};
  if (tid < 64) {
    #pragma unroll
    for (int p = 0; p < 4; ++p)
      tr[p] = trans[nxt * KTAG + pg * 4 + p];
  }
  // vl in registers: lane 4n holds vl[n]
  float vlreg = ((lane >> 2) == START_TAG) ? 0.f : NEGV;
  __syncthreads();

  for (int ch = 0; ch < 16; ++ch) {
    const float* src = feats + (size_t)ch * 256 * KTAG;
    #pragma unroll
    for (int i = 0; i < 4; ++i)
      *(float4*)&fch[(i * 256 + tid) * 4] = *(const float4*)&src[(i * 256 + tid) * 4];
    __syncthreads();

    if (tid < 64) {
      const int sbase = pg << 4;
      for (int tl = 0; tl < 256; ++tl) {
        const int t = ch * 256 + tl;
        const float s0 = __shfl(vlreg, sbase);
        const float s1 = __shfl(vlreg, sbase + 4);
        const float s2 = __shfl(vlreg, sbase + 8);
        const float s3 = __shfl(vlreg, sbase + 12);
        float best = s0 + tr[0]; int bp = pg * 4;
        float sc = s1 + tr[1]; if (sc > best) { best = sc; bp = pg * 4 + 1; }
        sc = s2 + tr[2]; if (sc > best) { best = sc; bp = pg * 4 + 2; }
        sc = s3 + tr[3]; if (sc > best) { best = sc; bp = pg * 4 + 3; }
        #pragma unroll
        for (int m = 1; m <= 2; m <<= 1) {      // merge groups, prefer lower idx
          const float ob = __shfl_xor(best, m);
          const int  obp = __shfl_xor(bp, m);
          if (ob > best || (ob == best && obp < bp)) { best = ob; bp = obp; }
        }
        const int nbp = __shfl(bp, (lane + 4) & 63);  // neighbor next's bp
        if (pg == 0 && (nxt & 1) == 0)
          bps8[t * 8 + (nxt >> 1)] = (unsigned char)(bp | (nbp << 4));
        const float fv = fch[tl * KTAG + nxt];
        vlreg = (pg == 0) ? (best + fv) : vlreg;
      }
    }
    __syncthreads();
  }

  if (tid < 64) {
    const float vfin = __shfl(vlreg, (lane & 15) << 2);
    float term = (lane < KTAG) ? (vfin + trans[END_TAG * KTAG + lane]) : -3.0e38f;
    int bt = (lane < KTAG) ? lane : KTAG;
    #pragma unroll
    for (int m = 1; m < 64; m <<= 1) {
      const float ot = __shfl_xor(term, m);
      const int  obt = __shfl_xor(bt, m);
      if (ot > term || (ot == term && obt < bt)) { term = ot; bt = obt; }
    }
    if (lane == 0) { out[0] = term; sbest = bt; }
  }
  __syncthreads();

  if (tid < 64) {
    const int L = lane;
    unsigned char cur[16];
    #pragma unroll
    for (int g = 0; g < 16; ++g) cur[g] = (unsigned char)g;
    for (int i = 63; i >= 0; --i) {
      const int t = L * 64 + i;
      #pragma unroll
      for (int g = 0; g < 16; ++g) {
        const unsigned char cc = cur[g];
        const unsigned char by = bps8[t * 8 + (cc >> 1)];
        cur[g] = (cc & 1) ? (by >> 4) : (by & 15);
      }
    }
    #pragma unroll
    for (int g = 0; g < 16; ++g) ml[L * 16 + g] = cur[g];
  }
  __syncthreads();

  if (tid == 0) {
    int r = sbest;
    rb[63] = (unsigned char)r;
    for (int cix = 62; cix >= 0; --cix) {
      r = ml[(cix + 1) * 16 + r];
      rb[cix] = (unsigned char)r;
    }
  }
  __syncthreads();

  if (tid < 64) {
    const int L = lane;
    int tag = rb[L];
    out[1 + L * 64 + 63] = (float)tag;
    for (int i = 62; i >= 0; --i) {
      const int t = L * 64 + i + 1;
      const unsigned char by = bps8[t * 8 + (tag >> 1)];
      tag = (tag & 1) ? (by >> 4) : (by & 15);
      out[1 + L * 64 + i] = (float)tag;
    }
  }
}

// ---------------------------------------------------------------------------
extern "C" void kernel_launch(void* const* d_in, const int* in_sizes, int n_in,
                              void* d_out, int out_size, void* d_ws, size_t ws_size,
                              hipStream_t stream) {
  (void)in_sizes; (void)n_in; (void)out_size; (void)ws_size;
  const int*   x      = (const int*)  d_in[0];
  const float* h0     = (const float*)d_in[1];
  const float* c0     = (const float*)d_in[2];
  const float* embed  = (const float*)d_in[3];
  const float* Wih_f  = (const float*)d_in[4];
  const float* Whh_f  = (const float*)d_in[5];
  const float* b_f    = (const float*)d_in[6];
  const float* Wih_b  = (const float*)d_in[7];
  const float* Whh_b  = (const float*)d_in[8];
  const float* b_b    = (const float*)d_in[9];
  const float* fc_w   = (const float*)d_in[10];
  const float* fc_b   = (const float*)d_in[11];
  const float* trans  = (const float*)d_in[12];
  float* out = (float*)d_out;

  char* ws = (char*)d_ws;
  unsigned long long* pairs  = (unsigned long long*)(ws + 0);      // 16 KB
  unsigned long long* pairs2 = (unsigned long long*)(ws + 16384);  // 16 KB
  int*   elect    = (int*)(ws + 32768);                            // 256 B
  float* feats    = (float*)(ws + 65536);                          // 256 KB
  float* hOut     = (float*)(ws + (1ull << 20));                   // 16 MB

  // zero pair tags (both buffers) + election state each launch
  hipMemsetAsync(ws, 0, 36864, stream);

  {
    void* args[] = {
      (void*)&Whh_f, (void*)&Whh_b, (void*)&Wih_f, (void*)&Wih_b,
      (void*)&b_f,   (void*)&b_b,   (void*)&h0,    (void*)&c0,
      (void*)&x,     (void*)&embed, (void*)&pairs, (void*)&pairs2,
      (void*)&hOut,  (void*)&elect
    };
    hipLaunchCooperativeKernel((const void*)lstm_kernel, dim3(NLAUNCH), dim3(256),
                               args, 0, stream);
  }

  feats_kernel<<<dim3(T_LEN / 16), 256, 0, stream>>>(hOut, fc_w, fc_b, feats);
  viterbi_kernel<<<dim3(1), 256, 0, stream>>>(feats, trans, out);
}

// Round 7
// 16311.220 us; speedup vs baseline: 2.3162x; 2.3162x over previous
//
#include <hip/hip_runtime.h>
#include <hip/hip_bf16.h>

#define T_LEN 4096
#define HID   512
#define EMB   256
#define KTAG  16
#define START_TAG 14
#define END_TAG   15
#define NEGV  (-10000.0f)
#define NTEAM   32   // elected team: 16 WGs per direction
#define NLAUNCH 256  // 1 block/CU; argmax XCD holds >= 32 by pigeonhole

// elect[] int indices
#define E_CENSUS 0   // 0..7
#define E_ARRIVE 8
#define E_CHOSEN 9
#define E_CLAIM  10
#define E_VOTE   12
#define E_XCC    16  // 16..47: per-slot xcc+1

typedef __attribute__((ext_vector_type(4))) unsigned int uint4v;

__device__ __forceinline__ unsigned long long packph(float h, unsigned tag) {
  return ((unsigned long long)tag << 32) | (unsigned long long)__float_as_uint(h);
}

// ---- FAST protocol (single XCD): write-through store to the XCD L2;
// poll = L1-invalidate + plain load so the L2's fresh copy is always read ----
__device__ __forceinline__ void pub_fast(unsigned long long* p, unsigned long long v) {
  asm volatile("global_store_dwordx2 %0, %1, off\n\t"
               "s_waitcnt vmcnt(0)" :: "v"(p), "v"(v) : "memory");
}
__device__ __forceinline__ void poll2_issue_fast(const unsigned long long* p, uint4v& d) {
  asm volatile("buffer_inv sc0\n\t"
               "global_load_dwordx4 %0, %1, off"
               : "=&v"(d) : "v"(p) : "memory");
}
__device__ __forceinline__ void poll2_wait_fast(uint4v& d) {
  asm volatile("s_waitcnt vmcnt(0)" : "+v"(d) :: "memory");
}
// ---- agent-scope ops (round-3 proven fallback) ----
__device__ __forceinline__ unsigned long long ld_pair_agent(const unsigned long long* p) {
  return __hip_atomic_load(p, __ATOMIC_RELAXED, __HIP_MEMORY_SCOPE_AGENT);
}
__device__ __forceinline__ void st_pair_agent(unsigned long long* p, unsigned long long v) {
  __hip_atomic_store(p, v, __ATOMIC_RELAXED, __HIP_MEMORY_SCOPE_AGENT);
}

// ---------------------------------------------------------------------------
// Main recurrence body. Team of 32 WGs; WG slot s: dir=s>>4, owns comps
// [32*(s&15), +32). Wave w = k-quarter; lane l handles rows (gate=l>>4,
// j=(l&15)) and (gate, (l&15)+16): 384 weight f32 in registers. Per step:
// poll own 128-comp chunk (2 tagged pairs/lane) -> LDS -> FMA -> one
// __syncthreads -> wave0 reduce/activation -> publish 32-pair burst.
// ---------------------------------------------------------------------------
template<int FAST>
__device__ void lstm_body(
    const float* __restrict__ Whh, const float* __restrict__ Wih,
    const float* __restrict__ bb,  const float* __restrict__ c0,
    const int*   __restrict__ x,   const float* __restrict__ embed,
    unsigned long long* __restrict__ pb, float* __restrict__ hOut,
    int dir, int sl, int w, int l)
{
  const int J0   = sl * 32;
  const int jl   = l & 15;
  const int gate = l >> 4;
  const int r0   = gate * HID + J0 + jl;
  const int r1   = r0 + 16;

  float wh0[128], wh1[128], we0[64], we1[64];
  {
    const float* p0 = Whh + (size_t)r0 * HID + w * 128;
    const float* p1 = Whh + (size_t)r1 * HID + w * 128;
    #pragma unroll
    for (int i = 0; i < 32; ++i) {
      *(float4*)&wh0[i*4] = *(const float4*)&p0[i*4];
      *(float4*)&wh1[i*4] = *(const float4*)&p1[i*4];
    }
    const float* q0 = Wih + (size_t)r0 * EMB + w * 64;
    const float* q1 = Wih + (size_t)r1 * EMB + w * 64;
    #pragma unroll
    for (int i = 0; i < 16; ++i) {
      *(float4*)&we0[i*4] = *(const float4*)&q0[i*4];
      *(float4*)&we1[i*4] = *(const float4*)&q1[i*4];
    }
  }
  // activation-lane constants (wave0 lanes 0..31 use them)
  const int ac = J0 + (l & 31);
  const float bi = bb[ac], bfg = bb[HID + ac];
  const float bg = bb[2*HID + ac], bo = bb[3*HID + ac];
  float cst = c0[dir * HID + ac];

  __shared__ float hl[4][128];
  __shared__ float el[4][64];
  __shared__ float ps[2][4][2][64];

  // prefetch emb quarter for step 0
  float epf;
  {
    const int tt0 = dir ? (T_LEN - 1) : 0;
    epf = embed[(size_t)x[tt0] * EMB + w * 64 + l];
  }

  unsigned spins = 0;

  for (int t = 0; t < T_LEN; ++t) {
    const int par = t & 1;
    const int tt  = dir ? (T_LEN - 1 - t) : t;

    // issue this wave's 2-pair poll early (in flight during emb work)
    unsigned long long* psrc = pb + ((par ^ 1) * 512) + w * 128 + 2 * l;
    uint4v fpr;
    unsigned long long sp0 = 0, sp1 = 0;
    if (FAST) {
      poll2_issue_fast(psrc, fpr);
    } else {
      sp0 = ld_pair_agent(&psrc[0]);
      sp1 = ld_pair_agent(&psrc[1]);
    }

    // stage emb quarter (intra-wave only)
    el[w][l] = epf;
    __builtin_amdgcn_wave_barrier();
    asm volatile("s_waitcnt lgkmcnt(0)" ::: "memory");
    __builtin_amdgcn_sched_barrier(0);

    // emb contribution overlaps the poll latency (chain order == round 3)
    float acc0 = 0.f, acc1 = 0.f;
    {
      const float* eseg = el[w];
      #pragma unroll
      for (int i = 0; i < 16; ++i) {
        float4 ev = *(const float4*)&eseg[i*4];
        acc0 += we0[i*4+0]*ev.x + we0[i*4+1]*ev.y + we0[i*4+2]*ev.z + we0[i*4+3]*ev.w;
        acc1 += we1[i*4+0]*ev.x + we1[i*4+1]*ev.y + we1[i*4+2]*ev.z + we1[i*4+3]*ev.w;
      }
    }

    // spin until this wave's chunk carries tag t+1 (h_{t-1})
    const unsigned tgt = (unsigned)(t + 1);
    if (FAST) {
      poll2_wait_fast(fpr);
      for (;;) {
        if (__all((fpr.y == tgt) && (fpr.w == tgt))) break;
        if (++spins > 2000000u) break;   // safety valve
        poll2_issue_fast(psrc, fpr);
        poll2_wait_fast(fpr);
      }
      sp0 = ((unsigned long long)fpr.y << 32) | fpr.x;
      sp1 = ((unsigned long long)fpr.w << 32) | fpr.z;
    } else {
      for (;;) {
        const bool f = ((unsigned)(sp0 >> 32) == tgt) && ((unsigned)(sp1 >> 32) == tgt);
        if (__all(f)) break;
        if (++spins > 2000000u) break;
        __builtin_amdgcn_s_sleep(1);
        sp0 = ld_pair_agent(&psrc[0]);
        sp1 = ld_pair_agent(&psrc[1]);
      }
    }

    // polled chunk -> per-wave LDS
    {
      float2 hv2;
      hv2.x = __uint_as_float((unsigned)sp0);
      hv2.y = __uint_as_float((unsigned)sp1);
      *(float2*)&hl[w][2*l] = hv2;
    }
    __builtin_amdgcn_wave_barrier();
    asm volatile("s_waitcnt lgkmcnt(0)" ::: "memory");
    __builtin_amdgcn_sched_barrier(0);

    // h contribution (same-address quads broadcast, conflict-free)
    {
      const float* hseg = hl[w];
      #pragma unroll
      for (int i = 0; i < 32; ++i) {
        float4 hv = *(const float4*)&hseg[i*4];
        acc0 += wh0[i*4+0]*hv.x + wh0[i*4+1]*hv.y + wh0[i*4+2]*hv.z + wh0[i*4+3]*hv.w;
        acc1 += wh1[i*4+0]*hv.x + wh1[i*4+1]*hv.y + wh1[i*4+2]*hv.z + wh1[i*4+3]*hv.w;
      }
    }

    ps[par][w][0][l] = acc0;
    ps[par][w][1][l] = acc1;
    __syncthreads();   // the one per-step intra-WG join

    if (w == 0) {
      const float t0 = (ps[par][0][0][l] + ps[par][1][0][l])
                     + (ps[par][2][0][l] + ps[par][3][0][l]);   // round-3 tree
      const float t1 = (ps[par][0][1][l] + ps[par][1][1][l])
                     + (ps[par][2][1][l] + ps[par][3][1][l]);
      const float a0 = __shfl(t0, jl),      b0 = __shfl(t1, jl);
      const float a1 = __shfl(t0, 16 + jl), b1 = __shfl(t1, 16 + jl);
      const float a2 = __shfl(t0, 32 + jl), b2 = __shfl(t1, 32 + jl);
      const float a3 = __shfl(t0, 48 + jl), b3 = __shfl(t1, 48 + jl);
      if (l < 32) {
        const bool hi = (l & 16) != 0;
        const float gi_ = (hi ? b0 : a0) + bi;
        const float gf_ = (hi ? b1 : a1) + bfg;
        const float gg_ = (hi ? b2 : a2) + bg;
        const float go_ = (hi ? b3 : a3) + bo;
        const float si = 1.f / (1.f + expf(-gi_));
        const float sf = 1.f / (1.f + expf(-gf_));
        const float so = 1.f / (1.f + expf(-go_));
        const float cn = sf * cst + si * tanhf(gg_);
        cst = cn;
        const float hv = so * tanhf(cn);
        const unsigned long long pk = packph(hv, (unsigned)(t + 2));
        if (FAST) pub_fast(&pb[par * 512 + J0 + l], pk);
        else      st_pair_agent(&pb[par * 512 + J0 + l], pk);
        hOut[((size_t)dir * T_LEN + tt) * HID + J0 + l] = hv;
      }
    }

    // prefetch next emb quarter (hides under next step's poll)
    if (t + 1 < T_LEN) {
      const int ttn = dir ? (T_LEN - 2 - t) : (t + 1);
      epf = embed[(size_t)x[ttn] * EMB + w * 64 + l];
    }
  }
}

// ---------------------------------------------------------------------------
// Election + verified-fast / agent-fallback dispatcher. All spins bounded;
// correctness never depends on placement, XCC_ID truth, or cache semantics:
// the handshake exercises the exact main-loop pattern and votes.
// ---------------------------------------------------------------------------
__global__ __launch_bounds__(256, 1) void lstm_kernel(
    const float* __restrict__ Whh_f, const float* __restrict__ Whh_b,
    const float* __restrict__ Wih_f, const float* __restrict__ Wih_b,
    const float* __restrict__ b_f,  const float* __restrict__ b_b,
    const float* __restrict__ h0,   const float* __restrict__ c0,
    const int*   __restrict__ x,    const float* __restrict__ embed,
    unsigned long long* __restrict__ pairs,    // fast-mode pair buffer
    unsigned long long* __restrict__ pairs2,   // agent-mode pair buffer
    float* __restrict__ hOut, int* __restrict__ elect)
{
  const int tid = threadIdx.x;
  __shared__ int s_slot, s_mode;
  __shared__ int s_ok[4];

  // ---- phase 1: census + choose + claim (tid 0) ----
  if (tid == 0) {
    int xcc;
    asm volatile("s_getreg_b32 %0, hwreg(HW_REG_XCC_ID)" : "=s"(xcc));
    xcc &= 7;
    __hip_atomic_fetch_add(&elect[E_CENSUS + xcc], 1, __ATOMIC_RELAXED, __HIP_MEMORY_SCOPE_AGENT);
    const int a = __hip_atomic_fetch_add(&elect[E_ARRIVE], 1, __ATOMIC_ACQ_REL, __HIP_MEMORY_SCOPE_AGENT);
    if (a == NLAUNCH - 1) {
      int best = 0, bc = -1;
      for (int i = 0; i < 8; ++i) {
        const int ci = __hip_atomic_load(&elect[E_CENSUS + i], __ATOMIC_RELAXED, __HIP_MEMORY_SCOPE_AGENT);
        if (ci > bc) { bc = ci; best = i; }
      }
      __hip_atomic_store(&elect[E_CHOSEN], best + 1, __ATOMIC_RELEASE, __HIP_MEMORY_SCOPE_AGENT);
    }
    int ch = 0;
    for (unsigned g = 0; g < 300000u; ++g) {
      ch = __hip_atomic_load(&elect[E_CHOSEN], __ATOMIC_ACQUIRE, __HIP_MEMORY_SCOPE_AGENT);
      if (ch) break;
      __builtin_amdgcn_s_sleep(2);
    }
    int slot = -1;
    if (ch == 0 || ch - 1 == xcc) {    // ch==0: degraded, claim anyway (agent mode will win)
      const int cl = __hip_atomic_fetch_add(&elect[E_CLAIM], 1, __ATOMIC_RELAXED, __HIP_MEMORY_SCOPE_AGENT);
      if (cl < NTEAM) slot = cl;
    }
    if (slot >= 0)
      __hip_atomic_store(&elect[E_XCC + slot], xcc + 1, __ATOMIC_RELEASE, __HIP_MEMORY_SCOPE_AGENT);
    s_slot = slot;
  }
  __syncthreads();
  const int slot = s_slot;
  if (slot < 0) return;   // not on the team

  const int dir = slot >> 4;
  const int sl  = slot & 15;
  const int J0  = sl * 32;
  const int w   = tid >> 6;
  const int l   = tid & 63;

  // ---- phase 2: membership + XCC uniformity (provisional mode) ----
  if (tid == 0) {
    int uni = 0;
    for (unsigned g = 0; g < 60000u; ++g) {
      int allnz = 1;
      for (int i = 0; i < NTEAM; ++i)
        if (!__hip_atomic_load(&elect[E_XCC + i], __ATOMIC_ACQUIRE, __HIP_MEMORY_SCOPE_AGENT)) { allnz = 0; break; }
      if (allnz) { uni = 1; break; }
      __builtin_amdgcn_s_sleep(2);
    }
    if (uni) {
      const int v0 = __hip_atomic_load(&elect[E_XCC], __ATOMIC_RELAXED, __HIP_MEMORY_SCOPE_AGENT);
      for (int i = 1; i < NTEAM; ++i)
        if (__hip_atomic_load(&elect[E_XCC + i], __ATOMIC_RELAXED, __HIP_MEMORY_SCOPE_AGENT) != v0) { uni = 0; break; }
    }
    s_mode = uni;
  }
  __syncthreads();

  // ---- phase 3: inv+load handshake (exact main-loop pattern) + vote ----
  if (s_mode) {
    if (w == 0 && l < 32)
      pub_fast(&pairs[(size_t)dir * 1024 + 512 + J0 + l],
               packph(h0[dir * HID + J0 + l], 1u));
    int okw = 0;
    {
      const unsigned long long* hp = pairs + (size_t)dir * 1024 + 512 + w * 128 + 2 * l;
      uint4v pr;
      for (unsigned g = 0; g < 20000u; ++g) {
        poll2_issue_fast(hp, pr);
        poll2_wait_fast(pr);
        if (__all((pr.y == 1u) && (pr.w == 1u))) { okw = 1; break; }
      }
    }
    if (l == 0) s_ok[w] = okw;
    __syncthreads();
    if (tid == 0) {
      const int ok = s_ok[0] & s_ok[1] & s_ok[2] & s_ok[3];
      __hip_atomic_fetch_add(&elect[E_VOTE], ok ? 1 : 0x10000, __ATOMIC_ACQ_REL, __HIP_MEMORY_SCOPE_AGENT);
      int v = 0;
      for (unsigned g = 0; g < 300000u; ++g) {
        v = __hip_atomic_load(&elect[E_VOTE], __ATOMIC_ACQUIRE, __HIP_MEMORY_SCOPE_AGENT);
        if ((v & 0xffff) + (v >> 16) >= NTEAM) break;
        __builtin_amdgcn_s_sleep(2);
      }
      s_mode = ((v >> 16) == 0 && (v & 0xffff) >= NTEAM) ? 1 : 0;
    }
    __syncthreads();
  }
  const int mode = s_mode;

  if (!mode) {   // agent fallback: fresh buffer, republish h_{-1}
    if (w == 0 && l < 32)
      st_pair_agent(&pairs2[(size_t)dir * 1024 + 512 + J0 + l],
                    packph(h0[dir * HID + J0 + l], 1u));
  }

  const float* Whh = dir ? Whh_b : Whh_f;
  const float* Wih = dir ? Wih_b : Wih_f;
  const float* bb  = dir ? b_b  : b_f;

  if (mode)
    lstm_body<1>(Whh, Wih, bb, c0, x, embed, pairs  + (size_t)dir * 1024, hOut, dir, sl, w, l);
  else
    lstm_body<0>(Whh, Wih, bb, c0, x, embed, pairs2 + (size_t)dir * 1024, hOut, dir, sl, w, l);
}

// ---------------------------------------------------------------------------
// feats[t][k] = concat(hf[t], hb[t]) . fc_w[k] + fc_b[k]
// ---------------------------------------------------------------------------
__global__ __launch_bounds__(256) void feats_kernel(
    const float* __restrict__ hOut, const float* __restrict__ fc_w,
    const float* __restrict__ fc_b, float* __restrict__ feats)
{
  const int tid = threadIdx.x;
  const int k   = tid & 15;
  const int tl  = tid >> 4;
  const int t   = blockIdx.x * 16 + tl;
  const float* hf = hOut + (size_t)t * HID;
  const float* hb = hOut + ((size_t)T_LEN + t) * HID;
  const float* wr = fc_w + (size_t)k * (2 * HID);
  float acc = fc_b[k];
  #pragma unroll 4
  for (int j = 0; j < HID; j += 4) {
    float4 hv = *(const float4*)&hf[j];
    float4 wv = *(const float4*)&wr[j];
    acc += hv.x*wv.x + hv.y*wv.y + hv.z*wv.z + hv.w*wv.w;
  }
  #pragma unroll 4
  for (int j = 0; j < HID; j += 4) {
    float4 hv = *(const float4*)&hb[j];
    float4 wv = *(const float4*)&wr[HID + j];
    acc += hv.x*wv.x + hv.y*wv.y + hv.z*wv.z + hv.w*wv.w;
  }
  feats[(size_t)t * KTAG + k] = acc;
}

// ---------------------------------------------------------------------------
// Viterbi: single block. DP state vl kept in wave-0 REGISTERS (lane 4n holds
// vl[n]); gathers via __shfl — no per-step LDS round trip. First-max tie
// rules preserved exactly. Backtrack via per-64-step chunk maps.
// ---------------------------------------------------------------------------
__global__ __launch_bounds__(256) void viterbi_kernel(
    const float* __restrict__ feats, const float* __restrict__ trans,
    float* __restrict__ out)
{
  __shared__ float fch[256 * KTAG];           // 16 KB feats chunk
  __shared__ unsigned char bps8[T_LEN * 8];   // 32 KB packed backpointers
  __shared__ unsigned char ml[64 * 16];       // chunk maps
  __shared__ unsigned char rb[64];            // chunk right-boundary tags
  __shared__ int sbest;

  const int tid  = threadIdx.x;
  const int lane = tid & 63;
  const int nxt  = lane >> 2;
  const int pg   = lane & 3;

  float tr[4] = {0.f, 0.f, 0.f, 0.f};
  if (tid < 64) {
    #pragma unroll
    for (int p = 0; p < 4; ++p)
      tr[p] = trans[nxt * KTAG + pg * 4 + p];
  }
  // vl in registers: lane 4n holds vl[n]
  float vlreg = ((lane >> 2) == START_TAG) ? 0.f : NEGV;
  __syncthreads();

  for (int ch = 0; ch < 16; ++ch) {
    const float* src = feats + (size_t)ch * 256 * KTAG;
    #pragma unroll
    for (int i = 0; i < 4; ++i)
      *(float4*)&fch[(i * 256 + tid) * 4] = *(const float4*)&src[(i * 256 + tid) * 4];
    __syncthreads();

    if (tid < 64) {
      const int sbase = pg << 4;
      for (int tl = 0; tl < 256; ++tl) {
        const int t = ch * 256 + tl;
        const float s0 = __shfl(vlreg, sbase);
        const float s1 = __shfl(vlreg, sbase + 4);
        const float s2 = __shfl(vlreg, sbase + 8);
        const float s3 = __shfl(vlreg, sbase + 12);
        float best = s0 + tr[0]; int bp = pg * 4;
        float sc = s1 + tr[1]; if (sc > best) { best = sc; bp = pg * 4 + 1; }
        sc = s2 + tr[2]; if (sc > best) { best = sc; bp = pg * 4 + 2; }
        sc = s3 + tr[3]; if (sc > best) { best = sc; bp = pg * 4 + 3; }
        #pragma unroll
        for (int m = 1; m <= 2; m <<= 1) {      // merge groups, prefer lower idx
          const float ob = __shfl_xor(best, m);
          const int  obp = __shfl_xor(bp, m);
          if (ob > best || (ob == best && obp < bp)) { best = ob; bp = obp; }
        }
        const int nbp = __shfl(bp, (lane + 4) & 63);  // neighbor next's bp
        if (pg == 0 && (nxt & 1) == 0)
          bps8[t * 8 + (nxt >> 1)] = (unsigned char)(bp | (nbp << 4));
        const float fv = fch[tl * KTAG + nxt];
        vlreg = (pg == 0) ? (best + fv) : vlreg;
      }
    }
    __syncthreads();
  }

  if (tid < 64) {
    const float vfin = __shfl(vlreg, (lane & 15) << 2);
    float term = (lane < KTAG) ? (vfin + trans[END_TAG * KTAG + lane]) : -3.0e38f;
    int bt = (lane < KTAG) ? lane : KTAG;
    #pragma unroll
    for (int m = 1; m < 64; m <<= 1) {
      const float ot = __shfl_xor(term, m);
      const int  obt = __shfl_xor(bt, m);
      if (ot > term || (ot == term && obt < bt)) { term = ot; bt = obt; }
    }
    if (lane == 0) { out[0] = term; sbest = bt; }
  }
  __syncthreads();

  if (tid < 64) {
    const int L = lane;
    unsigned char cur[16];
    #pragma unroll
    for (int g = 0; g < 16; ++g) cur[g] = (unsigned char)g;
    for (int i = 63; i >= 0; --i) {
      const int t = L * 64 + i;
      #pragma unroll
      for (int g = 0; g < 16; ++g) {
        const unsigned char cc = cur[g];
        const unsigned char by = bps8[t * 8 + (cc >> 1)];
        cur[g] = (cc & 1) ? (by >> 4) : (by & 15);
      }
    }
    #pragma unroll
    for (int g = 0; g < 16; ++g) ml[L * 16 + g] = cur[g];
  }
  __syncthreads();

  if (tid == 0) {
    int r = sbest;
    rb[63] = (unsigned char)r;
    for (int cix = 62; cix >= 0; --cix) {
      r = ml[(cix + 1) * 16 + r];
      rb[cix] = (unsigned char)r;
    }
  }
  __syncthreads();

  if (tid < 64) {
    const int L = lane;
    int tag = rb[L];
    out[1 + L * 64 + 63] = (float)tag;
    for (int i = 62; i >= 0; --i) {
      const int t = L * 64 + i + 1;
      const unsigned char by = bps8[t * 8 + (tag >> 1)];
      tag = (tag & 1) ? (by >> 4) : (by & 15);
      out[1 + L * 64 + i] = (float)tag;
    }
  }
}

// ---------------------------------------------------------------------------
extern "C" void kernel_launch(void* const* d_in, const int* in_sizes, int n_in,
                              void* d_out, int out_size, void* d_ws, size_t ws_size,
                              hipStream_t stream) {
  (void)in_sizes; (void)n_in; (void)out_size; (void)ws_size;
  const int*   x      = (const int*)  d_in[0];
  const float* h0     = (const float*)d_in[1];
  const float* c0     = (const float*)d_in[2];
  const float* embed  = (const float*)d_in[3];
  const float* Wih_f  = (const float*)d_in[4];
  const float* Whh_f  = (const float*)d_in[5];
  const float* b_f    = (const float*)d_in[6];
  const float* Wih_b  = (const float*)d_in[7];
  const float* Whh_b  = (const float*)d_in[8];
  const float* b_b    = (const float*)d_in[9];
  const float* fc_w   = (const float*)d_in[10];
  const float* fc_b   = (const float*)d_in[11];
  const float* trans  = (const float*)d_in[12];
  float* out = (float*)d_out;

  char* ws = (char*)d_ws;
  unsigned long long* pairs  = (unsigned long long*)(ws + 0);      // 16 KB
  unsigned long long* pairs2 = (unsigned long long*)(ws + 16384);  // 16 KB
  int*   elect    = (int*)(ws + 32768);                            // 256 B
  float* feats    = (float*)(ws + 65536);                          // 256 KB
  float* hOut     = (float*)(ws + (1ull << 20));                   // 16 MB

  // zero pair tags (both buffers) + election state each launch
  hipMemsetAsync(ws, 0, 36864, stream);

  {
    void* args[] = {
      (void*)&Whh_f, (void*)&Whh_b, (void*)&Wih_f, (void*)&Wih_b,
      (void*)&b_f,   (void*)&b_b,   (void*)&h0,    (void*)&c0,
      (void*)&x,     (void*)&embed, (void*)&pairs, (void*)&pairs2,
      (void*)&hOut,  (void*)&elect
    };
    hipLaunchCooperativeKernel((const void*)lstm_kernel, dim3(NLAUNCH), dim3(256),
                               args, 0, stream);
  }

  feats_kernel<<<dim3(T_LEN / 16), 256, 0, stream>>>(hOut, fc_w, fc_b, feats);
  viterbi_kernel<<<dim3(1), 256, 0, stream>>>(feats, trans, out);
}

// Round 9
// 10706.643 us; speedup vs baseline: 3.5286x; 1.5235x over previous
//
#include <hip/hip_runtime.h>
#include <hip/hip_bf16.h>

#define T_LEN 4096
#define HID   512
#define EMB   256
#define KTAG  16
#define START_TAG 14
#define END_TAG   15
#define NEGV  (-10000.0f)
#define NWG   64   // 32 workgroups per direction (round-3 structure)

__device__ __forceinline__ unsigned long long packph(float h, unsigned tag) {
  return ((unsigned long long)tag << 32) | (unsigned long long)__float_as_uint(h);
}
__device__ __forceinline__ unsigned long long ld_pair_agent(const unsigned long long* p) {
  return __hip_atomic_load(p, __ATOMIC_RELAXED, __HIP_MEMORY_SCOPE_AGENT);
}
__device__ __forceinline__ void st_pair_agent(unsigned long long* p, unsigned long long v) {
  __hip_atomic_store(p, v, __ATOMIC_RELAXED, __HIP_MEMORY_SCOPE_AGENT);
}
__device__ __forceinline__ unsigned ptag(unsigned long long v) { return (unsigned)(v >> 32); }

// ---------------------------------------------------------------------------
// Persistent bidirectional LSTM, barrier-free across WGs (round-3 protocol).
// 64 WGs x 256 threads. Wave w of each WG owns k-quarter w of all 64 rows
// (lane = row): it polls ONLY the 128 h-components it consumes (2 pairs per
// lane), via a 2-deep pipeline of relaxed agent-scope atomic loads (the
// compiler inserts minimal vmcnt waits -> detection granularity ~RT/2).
// Partial sums tree-reduce via parity-double-buffered LDS + one __syncthreads
// per step; wave 0 applies gates and publishes 16 comps as one burst.
// Poll-before-write bounds cross-WG skew to 1 step.
// ---------------------------------------------------------------------------
__global__ __launch_bounds__(256, 1) void lstm_kernel(
    const float* __restrict__ Whh_f, const float* __restrict__ Whh_b,
    const float* __restrict__ Wih_f, const float* __restrict__ Wih_b,
    const float* __restrict__ b_f,  const float* __restrict__ b_b,
    const float* __restrict__ h0,   const float* __restrict__ c0,
    const int*   __restrict__ x,    const float* __restrict__ embed,
    unsigned long long* __restrict__ pairs,   // [2 dir][2 parity][512]
    float* __restrict__ hOut)                 // [2 dir][T][512]
{
  const int wg   = blockIdx.x;
  const int dir  = wg >> 5;      // 0 fwd, 1 bwd
  const int sl   = wg & 31;
  const int J0   = sl * 16;
  const int tid  = threadIdx.x;
  const int w    = tid >> 6;     // wave 0..3 = k-quarter
  const int l    = tid & 63;     // local row: gate = l>>4, jloc = l&15
  const int jl   = l & 15;
  const int comp = J0 + jl;
  const int grow = (l >> 4) * HID + comp;   // global W row

  const float* Whh = dir ? Whh_b : Whh_f;
  const float* Wih = dir ? Wih_b : Wih_f;
  const float* bb  = dir ? b_b  : b_f;

  // this lane's k-quarter of its row, in registers
  float wh[128];
  {
    const float* wr = Whh + (size_t)grow * HID + w * 128;
    #pragma unroll
    for (int i = 0; i < 32; ++i)
      *(float4*)&wh[i*4] = *(const float4*)&wr[i*4];
  }
  float we[64];
  {
    const float* wr2 = Wih + (size_t)grow * EMB + w * 64;
    #pragma unroll
    for (int i = 0; i < 16; ++i)
      *(float4*)&we[i*4] = *(const float4*)&wr2[i*4];
  }
  const float bi = bb[comp],        bfg = bb[HID + comp];
  const float bg = bb[2*HID + comp], bo = bb[3*HID + comp];
  float c = c0[dir * HID + comp];           // meaningful in wave 0

  __shared__ float hl[4][128];   // per-wave h chunk
  __shared__ float el[4][64];    // per-wave emb quarter
  __shared__ float ps[2][4][64]; // parity-double-buffered partials

  unsigned long long* pb = pairs + (size_t)dir * 2 * 512;

  // publish h_{-1} (parity 1, tag 1); pairs buffer was memset to 0
  if (w == 0 && l < 16)
    st_pair_agent(&pb[512 + J0 + l], packph(h0[dir*HID + J0 + l], 1u));

  // prefetch emb quarter for step 0 (scalar per lane, coalesced per wave)
  float epf;
  {
    const int tt0 = dir ? (T_LEN - 1) : 0;
    epf = embed[(size_t)x[tt0] * EMB + w * 64 + l];
  }

  unsigned spins = 0;

  for (int t = 0; t < T_LEN; ++t) {
    const int par = t & 1;
    const int tt  = dir ? (T_LEN - 1 - t) : t;

    // 2-deep pipelined poll: two copies of the 2-pair poll in flight.
    // Relaxed agent atomics get no legalizer fences; the backend waits
    // vmcnt(2) before each check, so the two copies alternate at ~RT/2.
    unsigned long long* psrc = pb + ((par ^ 1) * 512) + w * 128 + 2 * l;
    unsigned long long a0 = ld_pair_agent(&psrc[0]);
    unsigned long long a1 = ld_pair_agent(&psrc[1]);
    unsigned long long b0 = ld_pair_agent(&psrc[0]);
    unsigned long long b1 = ld_pair_agent(&psrc[1]);

    // stage emb quarter (intra-wave only: waitcnt + sched fence, no barrier)
    el[w][l] = epf;
    __builtin_amdgcn_wave_barrier();
    asm volatile("s_waitcnt lgkmcnt(0)" ::: "memory");
    __builtin_amdgcn_sched_barrier(0);

    // emb contribution overlaps the poll latency (chain order == round 3)
    float acc = 0.f;
    {
      const float* eseg = el[w];
      #pragma unroll
      for (int i = 0; i < 16; ++i) {
        float4 ev = *(const float4*)&eseg[i*4];
        acc += we[i*4+0]*ev.x + we[i*4+1]*ev.y + we[i*4+2]*ev.z + we[i*4+3]*ev.w;
      }
    }

    // alternate-check the two in-flight poll copies until tags == t+1
    const unsigned tgt = (unsigned)(t + 1);
    unsigned long long sp0, sp1;
    for (;;) {
      if (__all((ptag(a0) == tgt) && (ptag(a1) == tgt))) { sp0 = a0; sp1 = a1; break; }
      if (++spins > 4000000u)                            { sp0 = a0; sp1 = a1; break; }
      a0 = ld_pair_agent(&psrc[0]);
      a1 = ld_pair_agent(&psrc[1]);
      if (__all((ptag(b0) == tgt) && (ptag(b1) == tgt))) { sp0 = b0; sp1 = b1; break; }
      if (++spins > 4000000u)                            { sp0 = b0; sp1 = b1; break; }
      b0 = ld_pair_agent(&psrc[0]);
      b1 = ld_pair_agent(&psrc[1]);
    }

    // polled chunk -> per-wave LDS
    {
      float2 hv2;
      hv2.x = __uint_as_float((unsigned)sp0);
      hv2.y = __uint_as_float((unsigned)sp1);
      *(float2*)&hl[w][2*l] = hv2;
    }
    __builtin_amdgcn_wave_barrier();
    asm volatile("s_waitcnt lgkmcnt(0)" ::: "memory");
    __builtin_amdgcn_sched_barrier(0);

    // h contribution (16-lane same-address reads broadcast, conflict-free)
    {
      const float* hseg = hl[w];
      #pragma unroll
      for (int i = 0; i < 32; ++i) {
        float4 hv = *(const float4*)&hseg[i*4];
        acc += wh[i*4+0]*hv.x + wh[i*4+1]*hv.y + wh[i*4+2]*hv.z + wh[i*4+3]*hv.w;
      }
    }

    ps[par][w][l] = acc;
    __syncthreads();   // the one per-step intra-WG join

    if (w == 0) {
      const float q0 = ps[par][0][l], q1 = ps[par][1][l];
      const float q2 = ps[par][2][l], q3 = ps[par][3][l];
      const float tot = (q0 + q1) + (q2 + q3);   // same tree as round 3
      const float g0 = __shfl(tot, jl);          // gate i row
      const float g1 = __shfl(tot, jl + 16);     // gate f
      const float g2 = __shfl(tot, jl + 32);     // gate g
      const float g3 = __shfl(tot, jl + 48);     // gate o
      const float gi_ = g0 + bi, gf_ = g1 + bfg, gg_ = g2 + bg, go_ = g3 + bo;
      const float si = 1.f / (1.f + expf(-gi_));
      const float sf = 1.f / (1.f + expf(-gf_));
      const float so = 1.f / (1.f + expf(-go_));
      const float cn = sf * c + si * tanhf(gg_);
      c = cn;
      const float hv = so * tanhf(cn);
      if (l < 16) {
        st_pair_agent(&pb[par * 512 + J0 + l], packph(hv, (unsigned)(t + 2)));
        hOut[((size_t)dir * T_LEN + tt) * HID + J0 + l] = hv;
      }
    }

    // prefetch next emb quarter (hides under next step's poll)
    if (t + 1 < T_LEN) {
      const int ttn = dir ? (T_LEN - 2 - t) : (t + 1);
      epf = embed[(size_t)x[ttn] * EMB + w * 64 + l];
    }
  }
}

// ---------------------------------------------------------------------------
// feats[t][k] = concat(hf[t], hb[t]) . fc_w[k] + fc_b[k]
// ---------------------------------------------------------------------------
__global__ __launch_bounds__(256) void feats_kernel(
    const float* __restrict__ hOut, const float* __restrict__ fc_w,
    const float* __restrict__ fc_b, float* __restrict__ feats)
{
  const int tid = threadIdx.x;
  const int k   = tid & 15;
  const int tl  = tid >> 4;
  const int t   = blockIdx.x * 16 + tl;
  const float* hf = hOut + (size_t)t * HID;
  const float* hb = hOut + ((size_t)T_LEN + t) * HID;
  const float* wr = fc_w + (size_t)k * (2 * HID);
  float acc = fc_b[k];
  #pragma unroll 4
  for (int j = 0; j < HID; j += 4) {
    float4 hv = *(const float4*)&hf[j];
    float4 wv = *(const float4*)&wr[j];
    acc += hv.x*wv.x + hv.y*wv.y + hv.z*wv.z + hv.w*wv.w;
  }
  #pragma unroll 4
  for (int j = 0; j < HID; j += 4) {
    float4 hv = *(const float4*)&hb[j];
    float4 wv = *(const float4*)&wr[HID + j];
    acc += hv.x*wv.x + hv.y*wv.y + hv.z*wv.z + hv.w*wv.w;
  }
  feats[(size_t)t * KTAG + k] = acc;
}

// ---------------------------------------------------------------------------
// Viterbi: single block. DP state vl kept in wave-0 REGISTERS (lane 4n holds
// vl[n]); gathers via __shfl — no per-step LDS round trip. First-max tie
// rules preserved exactly. Backtrack via per-64-step chunk maps.
// (Verbatim from rounds 5-7, all passed.)
// ---------------------------------------------------------------------------
__global__ __launch_bounds__(256) void viterbi_kernel(
    const float* __restrict__ feats, const float* __restrict__ trans,
    float* __restrict__ out)
{
  __shared__ float fch[256 * KTAG];           // 16 KB feats chunk
  __shared__ unsigned char bps8[T_LEN * 8];   // 32 KB packed backpointers
  __shared__ unsigned char ml[64 * 16];       // chunk maps
  __shared__ unsigned char rb[64];            // chunk right-boundary tags
  __shared__ int sbest;

  const int tid  = threadIdx.x;
  const int lane = tid & 63;
  const int nxt  = lane >> 2;
  const int pg   = lane & 3;

  float tr[4] = {0.f, 0.f, 0.f, 0.f};
  if (tid < 64) {
    #pragma unroll
    for (int p = 0; p < 4; ++p)
      tr[p] = trans[nxt * KTAG + pg * 4 + p];
  }
  // vl in registers: lane 4n holds vl[n]
  float vlreg = ((lane >> 2) == START_TAG) ? 0.f : NEGV;
  __syncthreads();

  for (int ch = 0; ch < 16; ++ch) {
    const float* src = feats + (size_t)ch * 256 * KTAG;
    #pragma unroll
    for (int i = 0; i < 4; ++i)
      *(float4*)&fch[(i * 256 + tid) * 4] = *(const float4*)&src[(i * 256 + tid) * 4];
    __syncthreads();

    if (tid < 64) {
      const int sbase = pg << 4;
      for (int tl = 0; tl < 256; ++tl) {
        const int t = ch * 256 + tl;
        const float s0 = __shfl(vlreg, sbase);
        const float s1 = __shfl(vlreg, sbase + 4);
        const float s2 = __shfl(vlreg, sbase + 8);
        const float s3 = __shfl(vlreg, sbase + 12);
        float best = s0 + tr[0]; int bp = pg * 4;
        float sc = s1 + tr[1]; if (sc > best) { best = sc; bp = pg * 4 + 1; }
        sc = s2 + tr[2]; if (sc > best) { best = sc; bp = pg * 4 + 2; }
        sc = s3 + tr[3]; if (sc > best) { best = sc; bp = pg * 4 + 3; }
        #pragma unroll
        for (int m = 1; m <= 2; m <<= 1) {      // merge groups, prefer lower idx
          const float ob = __shfl_xor(best, m);
          const int  obp = __shfl_xor(bp, m);
          if (ob > best || (ob == best && obp < bp)) { best = ob; bp = obp; }
        }
        const int nbp = __shfl(bp, (lane + 4) & 63);  // neighbor next's bp
        if (pg == 0 && (nxt & 1) == 0)
          bps8[t * 8 + (nxt >> 1)] = (unsigned char)(bp | (nbp << 4));
        const float fv = fch[tl * KTAG + nxt];
        vlreg = (pg == 0) ? (best + fv) : vlreg;
      }
    }
    __syncthreads();
  }

  if (tid < 64) {
    const float vfin = __shfl(vlreg, (lane & 15) << 2);
    float term = (lane < KTAG) ? (vfin + trans[END_TAG * KTAG + lane]) : -3.0e38f;
    int bt = (lane < KTAG) ? lane : KTAG;
    #pragma unroll
    for (int m = 1; m < 64; m <<= 1) {
      const float ot = __shfl_xor(term, m);
      const int  obt = __shfl_xor(bt, m);
      if (ot > term || (ot == term && obt < bt)) { term = ot; bt = obt; }
    }
    if (lane == 0) { out[0] = term; sbest = bt; }
  }
  __syncthreads();

  if (tid < 64) {
    const int L = lane;
    unsigned char cur[16];
    #pragma unroll
    for (int g = 0; g < 16; ++g) cur[g] = (unsigned char)g;
    for (int i = 63; i >= 0; --i) {
      const int t = L * 64 + i;
      #pragma unroll
      for (int g = 0; g < 16; ++g) {
        const unsigned char cc = cur[g];
        const unsigned char by = bps8[t * 8 + (cc >> 1)];
        cur[g] = (cc & 1) ? (by >> 4) : (by & 15);
      }
    }
    #pragma unroll
    for (int g = 0; g < 16; ++g) ml[L * 16 + g] = cur[g];
  }
  __syncthreads();

  if (tid == 0) {
    int r = sbest;
    rb[63] = (unsigned char)r;
    for (int cix = 62; cix >= 0; --cix) {
      r = ml[(cix + 1) * 16 + r];
      rb[cix] = (unsigned char)r;
    }
  }
  __syncthreads();

  if (tid < 64) {
    const int L = lane;
    int tag = rb[L];
    out[1 + L * 64 + 63] = (float)tag;
    for (int i = 62; i >= 0; --i) {
      const int t = L * 64 + i + 1;
      const unsigned char by = bps8[t * 8 + (tag >> 1)];
      tag = (tag & 1) ? (by >> 4) : (by & 15);
      out[1 + L * 64 + i] = (float)tag;
    }
  }
}

// ---------------------------------------------------------------------------
extern "C" void kernel_launch(void* const* d_in, const int* in_sizes, int n_in,
                              void* d_out, int out_size, void* d_ws, size_t ws_size,
                              hipStream_t stream) {
  (void)in_sizes; (void)n_in; (void)out_size; (void)ws_size;
  const int*   x      = (const int*)  d_in[0];
  const float* h0     = (const float*)d_in[1];
  const float* c0     = (const float*)d_in[2];
  const float* embed  = (const float*)d_in[3];
  const float* Wih_f  = (const float*)d_in[4];
  const float* Whh_f  = (const float*)d_in[5];
  const float* b_f    = (const float*)d_in[6];
  const float* Wih_b  = (const float*)d_in[7];
  const float* Whh_b  = (const float*)d_in[8];
  const float* b_b    = (const float*)d_in[9];
  const float* fc_w   = (const float*)d_in[10];
  const float* fc_b   = (const float*)d_in[11];
  const float* trans  = (const float*)d_in[12];
  float* out = (float*)d_out;

  char* ws = (char*)d_ws;
  unsigned long long* pairs = (unsigned long long*)(ws + 0);  // 16 KB
  float* feats    = (float*)(ws + 65536);                     // 256 KB
  float* hOut     = (float*)(ws + (1ull << 20));              // 16 MB

  // zero all tags so stale/poison data can never satisfy a poll
  hipMemsetAsync(pairs, 0, 2 * 2 * 512 * sizeof(unsigned long long), stream);

  {
    void* args[] = {
      (void*)&Whh_f, (void*)&Whh_b, (void*)&Wih_f, (void*)&Wih_b,
      (void*)&b_f,   (void*)&b_b,   (void*)&h0,    (void*)&c0,
      (void*)&x,     (void*)&embed, (void*)&pairs, (void*)&hOut
    };
    hipLaunchCooperativeKernel((const void*)lstm_kernel, dim3(NWG), dim3(256),
                               args, 0, stream);
  }

  feats_kernel<<<dim3(T_LEN / 16), 256, 0, stream>>>(hOut, fc_w, fc_b, feats);
  viterbi_kernel<<<dim3(1), 256, 0, stream>>>(feats, trans, out);
}

// Round 11
// 10185.464 us; speedup vs baseline: 3.7092x; 1.0512x over previous
//
#include <hip/hip_runtime.h>
#include <hip/hip_bf16.h>

#define T_LEN 4096
#define HID   512
#define EMB   256
#define KTAG  16
#define START_TAG 14
#define END_TAG   15
#define NEGV  (-10000.0f)
#define NWG   64   // 32 workgroups per direction (round-3 structure)

__device__ __forceinline__ unsigned long long packph(float h, unsigned tag) {
  return ((unsigned long long)tag << 32) | (unsigned long long)__float_as_uint(h);
}
__device__ __forceinline__ unsigned long long ld_pair_agent(const unsigned long long* p) {
  return __hip_atomic_load(p, __ATOMIC_RELAXED, __HIP_MEMORY_SCOPE_AGENT);
}
__device__ __forceinline__ void st_pair_agent(unsigned long long* p, unsigned long long v) {
  __hip_atomic_store(p, v, __ATOMIC_RELAXED, __HIP_MEMORY_SCOPE_AGENT);
}
__device__ __forceinline__ unsigned ptag(unsigned long long v) { return (unsigned)(v >> 32); }

// ---------------------------------------------------------------------------
// Persistent bidirectional LSTM, barrier-free across WGs (round-3 protocol,
// single-poll spin — the proven fastest). 64 WGs x 256 threads. Wave w of
// each WG owns k-quarter w of all 64 rows (lane = row): it polls ONLY the
// 128 h-components it consumes (2 tagged pairs per lane). Partial sums
// tree-reduce via parity-double-buffered LDS + one __syncthreads per step;
// wave 0 applies gates and publishes 16 comps as one burst.
// DELTA vs round 3: the h-contribution uses 4 independent FMA chains
// (32 serial FMAs each) instead of one 128-FMA chain — cuts ~150ns of
// dependent-latency off the post-detect critical path per step.
// ---------------------------------------------------------------------------
__global__ __launch_bounds__(256, 1) void lstm_kernel(
    const float* __restrict__ Whh_f, const float* __restrict__ Whh_b,
    const float* __restrict__ Wih_f, const float* __restrict__ Wih_b,
    const float* __restrict__ b_f,  const float* __restrict__ b_b,
    const float* __restrict__ h0,   const float* __restrict__ c0,
    const int*   __restrict__ x,    const float* __restrict__ embed,
    unsigned long long* __restrict__ pairs,   // [2 dir][2 parity][512]
    float* __restrict__ hOut)                 // [2 dir][T][512]
{
  const int wg   = blockIdx.x;
  const int dir  = wg >> 5;      // 0 fwd, 1 bwd
  const int sl   = wg & 31;
  const int J0   = sl * 16;
  const int tid  = threadIdx.x;
  const int w    = tid >> 6;     // wave 0..3 = k-quarter
  const int l    = tid & 63;     // local row: gate = l>>4, jloc = l&15
  const int jl   = l & 15;
  const int comp = J0 + jl;
  const int grow = (l >> 4) * HID + comp;   // global W row

  const float* Whh = dir ? Whh_b : Whh_f;
  const float* Wih = dir ? Wih_b : Wih_f;
  const float* bb  = dir ? b_b  : b_f;

  // this lane's k-quarter of its row, in registers
  float wh[128];
  {
    const float* wr = Whh + (size_t)grow * HID + w * 128;
    #pragma unroll
    for (int i = 0; i < 32; ++i)
      *(float4*)&wh[i*4] = *(const float4*)&wr[i*4];
  }
  float we[64];
  {
    const float* wr2 = Wih + (size_t)grow * EMB + w * 64;
    #pragma unroll
    for (int i = 0; i < 16; ++i)
      *(float4*)&we[i*4] = *(const float4*)&wr2[i*4];
  }
  const float bi = bb[comp],        bfg = bb[HID + comp];
  const float bg = bb[2*HID + comp], bo = bb[3*HID + comp];
  float c = c0[dir * HID + comp];           // meaningful in wave 0

  __shared__ float hl[4][128];   // per-wave h chunk
  __shared__ float el[4][64];    // per-wave emb quarter
  __shared__ float ps[2][4][64]; // parity-double-buffered partials

  unsigned long long* pb = pairs + (size_t)dir * 2 * 512;

  // publish h_{-1} (parity 1, tag 1); pairs buffer was memset to 0
  if (w == 0 && l < 16)
    st_pair_agent(&pb[512 + J0 + l], packph(h0[dir*HID + J0 + l], 1u));

  // prefetch emb quarter for step 0 (scalar per lane, coalesced per wave)
  float epf;
  {
    const int tt0 = dir ? (T_LEN - 1) : 0;
    epf = embed[(size_t)x[tt0] * EMB + w * 64 + l];
  }

  unsigned spins = 0;

  for (int t = 0; t < T_LEN; ++t) {
    const int par = t & 1;
    const int tt  = dir ? (T_LEN - 1 - t) : t;

    // issue this wave's 2-pair poll early (in flight during emb work)
    unsigned long long* psrc = pb + ((par ^ 1) * 512) + w * 128 + 2 * l;
    unsigned long long sp0 = ld_pair_agent(&psrc[0]);
    unsigned long long sp1 = ld_pair_agent(&psrc[1]);

    // stage emb quarter (intra-wave only: waitcnt + sched fence, no barrier)
    el[w][l] = epf;
    __builtin_amdgcn_wave_barrier();
    asm volatile("s_waitcnt lgkmcnt(0)" ::: "memory");
    __builtin_amdgcn_sched_barrier(0);

    // emb contribution overlaps the poll latency (off the critical path)
    float acc = 0.f;
    {
      const float* eseg = el[w];
      #pragma unroll
      for (int i = 0; i < 16; ++i) {
        float4 ev = *(const float4*)&eseg[i*4];
        acc += we[i*4+0]*ev.x + we[i*4+1]*ev.y + we[i*4+2]*ev.z + we[i*4+3]*ev.w;
      }
    }

    // spin until this wave's 128-word chunk carries tag t+1 (h_{t-1})
    const unsigned tgt = (unsigned)(t + 1);
    for (;;) {
      const bool f = (ptag(sp0) == tgt) && (ptag(sp1) == tgt);
      if (__all(f)) break;
      if (++spins > 2000000u) break;   // safety valve
      __builtin_amdgcn_s_sleep(1);
      sp0 = ld_pair_agent(&psrc[0]);
      sp1 = ld_pair_agent(&psrc[1]);
    }

    // polled chunk -> per-wave LDS
    {
      float2 hv2;
      hv2.x = __uint_as_float((unsigned)sp0);
      hv2.y = __uint_as_float((unsigned)sp1);
      *(float2*)&hl[w][2*l] = hv2;
    }
    __builtin_amdgcn_wave_barrier();
    asm volatile("s_waitcnt lgkmcnt(0)" ::: "memory");
    __builtin_amdgcn_sched_barrier(0);

    // h contribution: 4 independent FMA chains (32 serial FMAs each),
    // combined by a 2-level tree. Same-address LDS reads broadcast.
    {
      const float* hseg = hl[w];
      float a0 = 0.f, a1 = 0.f, a2 = 0.f, a3 = 0.f;
      #pragma unroll
      for (int i = 0; i < 8; ++i) {
        float4 h0v = *(const float4*)&hseg[(4*i+0)*4];
        float4 h1v = *(const float4*)&hseg[(4*i+1)*4];
        float4 h2v = *(const float4*)&hseg[(4*i+2)*4];
        float4 h3v = *(const float4*)&hseg[(4*i+3)*4];
        const float* w0 = &wh[(4*i+0)*4];
        const float* w1 = &wh[(4*i+1)*4];
        const float* w2 = &wh[(4*i+2)*4];
        const float* w3 = &wh[(4*i+3)*4];
        a0 += w0[0]*h0v.x + w0[1]*h0v.y + w0[2]*h0v.z + w0[3]*h0v.w;
        a1 += w1[0]*h1v.x + w1[1]*h1v.y + w1[2]*h1v.z + w1[3]*h1v.w;
        a2 += w2[0]*h2v.x + w2[1]*h2v.y + w2[2]*h2v.z + w2[3]*h2v.w;
        a3 += w3[0]*h3v.x + w3[1]*h3v.y + w3[2]*h3v.z + w3[3]*h3v.w;
      }
      acc += (a0 + a1) + (a2 + a3);
    }

    ps[par][w][l] = acc;
    __syncthreads();   // the one per-step intra-WG join

    if (w == 0) {
      const float q0 = ps[par][0][l], q1 = ps[par][1][l];
      const float q2 = ps[par][2][l], q3 = ps[par][3][l];
      const float tot = (q0 + q1) + (q2 + q3);   // same tree as round 3
      const float g0 = __shfl(tot, jl);          // gate i row
      const float g1 = __shfl(tot, jl + 16);     // gate f
      const float g2 = __shfl(tot, jl + 32);     // gate g
      const float g3 = __shfl(tot, jl + 48);     // gate o
      const float gi_ = g0 + bi, gf_ = g1 + bfg, gg_ = g2 + bg, go_ = g3 + bo;
      const float si = 1.f / (1.f + expf(-gi_));
      const float sf = 1.f / (1.f + expf(-gf_));
      const float so = 1.f / (1.f + expf(-go_));
      const float cn = sf * c + si * tanhf(gg_);
      c = cn;
      const float hv = so * tanhf(cn);
      if (l < 16) {
        st_pair_agent(&pb[par * 512 + J0 + l], packph(hv, (unsigned)(t + 2)));
        hOut[((size_t)dir * T_LEN + tt) * HID + J0 + l] = hv;
      }
    }

    // prefetch next emb quarter (hides under next step's poll)
    if (t + 1 < T_LEN) {
      const int ttn = dir ? (T_LEN - 2 - t) : (t + 1);
      epf = embed[(size_t)x[ttn] * EMB + w * 64 + l];
    }
  }
}

// ---------------------------------------------------------------------------
// feats[t][k] = concat(hf[t], hb[t]) . fc_w[k] + fc_b[k]
// ---------------------------------------------------------------------------
__global__ __launch_bounds__(256) void feats_kernel(
    const float* __restrict__ hOut, const float* __restrict__ fc_w,
    const float* __restrict__ fc_b, float* __restrict__ feats)
{
  const int tid = threadIdx.x;
  const int k   = tid & 15;
  const int tl  = tid >> 4;
  const int t   = blockIdx.x * 16 + tl;
  const float* hf = hOut + (size_t)t * HID;
  const float* hb = hOut + ((size_t)T_LEN + t) * HID;
  const float* wr = fc_w + (size_t)k * (2 * HID);
  float acc = fc_b[k];
  #pragma unroll 4
  for (int j = 0; j < HID; j += 4) {
    float4 hv = *(const float4*)&hf[j];
    float4 wv = *(const float4*)&wr[j];
    acc += hv.x*wv.x + hv.y*wv.y + hv.z*wv.z + hv.w*wv.w;
  }
  #pragma unroll 4
  for (int j = 0; j < HID; j += 4) {
    float4 hv = *(const float4*)&hb[j];
    float4 wv = *(const float4*)&wr[HID + j];
    acc += hv.x*wv.x + hv.y*wv.y + hv.z*wv.z + hv.w*wv.w;
  }
  feats[(size_t)t * KTAG + k] = acc;
}

// ---------------------------------------------------------------------------
// Viterbi: single block. DP state vl kept in wave-0 REGISTERS (lane 4n holds
// vl[n]); gathers via __shfl — no per-step LDS round trip. First-max tie
// rules preserved exactly. Backtrack via per-64-step chunk maps.
// (Verbatim from rounds 5-7/9, all passed.)
// ---------------------------------------------------------------------------
__global__ __launch_bounds__(256) void viterbi_kernel(
    const float* __restrict__ feats, const float* __restrict__ trans,
    float* __restrict__ out)
{
  __shared__ float fch[256 * KTAG];           // 16 KB feats chunk
  __shared__ unsigned char bps8[T_LEN * 8];   // 32 KB packed backpointers
  __shared__ unsigned char ml[64 * 16];       // chunk maps
  __shared__ unsigned char rb[64];            // chunk right-boundary tags
  __shared__ int sbest;

  const int tid  = threadIdx.x;
  const int lane = tid & 63;
  const int nxt  = lane >> 2;
  const int pg   = lane & 3;

  float tr[4] = {0.f, 0.f, 0.f, 0.f};
  if (tid < 64) {
    #pragma unroll
    for (int p = 0; p < 4; ++p)
      tr[p] = trans[nxt * KTAG + pg * 4 + p];
  }
  // vl in registers: lane 4n holds vl[n]
  float vlreg = ((lane >> 2) == START_TAG) ? 0.f : NEGV;
  __syncthreads();

  for (int ch = 0; ch < 16; ++ch) {
    const float* src = feats + (size_t)ch * 256 * KTAG;
    #pragma unroll
    for (int i = 0; i < 4; ++i)
      *(float4*)&fch[(i * 256 + tid) * 4] = *(const float4*)&src[(i * 256 + tid) * 4];
    __syncthreads();

    if (tid < 64) {
      const int sbase = pg << 4;
      for (int tl = 0; tl < 256; ++tl) {
        const int t = ch * 256 + tl;
        const float s0 = __shfl(vlreg, sbase);
        const float s1 = __shfl(vlreg, sbase + 4);
        const float s2 = __shfl(vlreg, sbase + 8);
        const float s3 = __shfl(vlreg, sbase + 12);
        float best = s0 + tr[0]; int bp = pg * 4;
        float sc = s1 + tr[1]; if (sc > best) { best = sc; bp = pg * 4 + 1; }
        sc = s2 + tr[2]; if (sc > best) { best = sc; bp = pg * 4 + 2; }
        sc = s3 + tr[3]; if (sc > best) { best = sc; bp = pg * 4 + 3; }
        #pragma unroll
        for (int m = 1; m <= 2; m <<= 1) {      // merge groups, prefer lower idx
          const float ob = __shfl_xor(best, m);
          const int  obp = __shfl_xor(bp, m);
          if (ob > best || (ob == best && obp < bp)) { best = ob; bp = obp; }
        }
        const int nbp = __shfl(bp, (lane + 4) & 63);  // neighbor next's bp
        if (pg == 0 && (nxt & 1) == 0)
          bps8[t * 8 + (nxt >> 1)] = (unsigned char)(bp | (nbp << 4));
        const float fv = fch[tl * KTAG + nxt];
        vlreg = (pg == 0) ? (best + fv) : vlreg;
      }
    }
    __syncthreads();
  }

  if (tid < 64) {
    const float vfin = __shfl(vlreg, (lane & 15) << 2);
    float term = (lane < KTAG) ? (vfin + trans[END_TAG * KTAG + lane]) : -3.0e38f;
    int bt = (lane < KTAG) ? lane : KTAG;
    #pragma unroll
    for (int m = 1; m < 64; m <<= 1) {
      const float ot = __shfl_xor(term, m);
      const int  obt = __shfl_xor(bt, m);
      if (ot > term || (ot == term && obt < bt)) { term = ot; bt = obt; }
    }
    if (lane == 0) { out[0] = term; sbest = bt; }
  }
  __syncthreads();

  if (tid < 64) {
    const int L = lane;
    unsigned char cur[16];
    #pragma unroll
    for (int g = 0; g < 16; ++g) cur[g] = (unsigned char)g;
    for (int i = 63; i >= 0; --i) {
      const int t = L * 64 + i;
      #pragma unroll
      for (int g = 0; g < 16; ++g) {
        const unsigned char cc = cur[g];
        const unsigned char by = bps8[t * 8 + (cc >> 1)];
        cur[g] = (cc & 1) ? (by >> 4) : (by & 15);
      }
    }
    #pragma unroll
    for (int g = 0; g < 16; ++g) ml[L * 16 + g] = cur[g];
  }
  __syncthreads();

  if (tid == 0) {
    int r = sbest;
    rb[63] = (unsigned char)r;
    for (int cix = 62; cix >= 0; --cix) {
      r = ml[(cix + 1) * 16 + r];
      rb[cix] = (unsigned char)r;
    }
  }
  __syncthreads();

  if (tid < 64) {
    const int L = lane;
    int tag = rb[L];
    out[1 + L * 64 + 63] = (float)tag;
    for (int i = 62; i >= 0; --i) {
      const int t = L * 64 + i + 1;
      const unsigned char by = bps8[t * 8 + (tag >> 1)];
      tag = (tag & 1) ? (by >> 4) : (by & 15);
      out[1 + L * 64 + i] = (float)tag;
    }
  }
}

// ---------------------------------------------------------------------------
extern "C" void kernel_launch(void* const* d_in, const int* in_sizes, int n_in,
                              void* d_out, int out_size, void* d_ws, size_t ws_size,
                              hipStream_t stream) {
  (void)in_sizes; (void)n_in; (void)out_size; (void)ws_size;
  const int*   x      = (const int*)  d_in[0];
  const float* h0     = (const float*)d_in[1];
  const float* c0     = (const float*)d_in[2];
  const float* embed  = (const float*)d_in[3];
  const float* Wih_f  = (const float*)d_in[4];
  const float* Whh_f  = (const float*)d_in[5];
  const float* b_f    = (const float*)d_in[6];
  const float* Wih_b  = (const float*)d_in[7];
  const float* Whh_b  = (const float*)d_in[8];
  const float* b_b    = (const float*)d_in[9];
  const float* fc_w   = (const float*)d_in[10];
  const float* fc_b   = (const float*)d_in[11];
  const float* trans  = (const float*)d_in[12];
  float* out = (float*)d_out;

  char* ws = (char*)d_ws;
  unsigned long long* pairs = (unsigned long long*)(ws + 0);  // 16 KB
  float* feats    = (float*)(ws + 65536);                     // 256 KB
  float* hOut     = (float*)(ws + (1ull << 20));              // 16 MB

  // zero all tags so stale/poison data can never satisfy a poll
  hipMemsetAsync(pairs, 0, 2 * 2 * 512 * sizeof(unsigned long long), stream);

  {
    void* args[] = {
      (void*)&Whh_f, (void*)&Whh_b, (void*)&Wih_f, (void*)&Wih_b,
      (void*)&b_f,   (void*)&b_b,   (void*)&h0,    (void*)&c0,
      (void*)&x,     (void*)&embed, (void*)&pairs, (void*)&hOut
    };
    hipLaunchCooperativeKernel((const void*)lstm_kernel, dim3(NWG), dim3(256),
                               args, 0, stream);
  }

  feats_kernel<<<dim3(T_LEN / 16), 256, 0, stream>>>(hOut, fc_w, fc_b, feats);
  viterbi_kernel<<<dim3(1), 256, 0, stream>>>(feats, trans, out);
}

// Round 12
// 9696.485 us; speedup vs baseline: 3.8962x; 1.0504x over previous
//
#include <hip/hip_runtime.h>
#include <hip/hip_bf16.h>

#define T_LEN 4096
#define HID   512
#define EMB   256
#define KTAG  16
#define START_TAG 14
#define END_TAG   15
#define NEGV  (-10000.0f)
#define NWG   64   // 32 workgroups per direction (round-3 structure)

__device__ __forceinline__ unsigned long long packph(float h, unsigned tag) {
  return ((unsigned long long)tag << 32) | (unsigned long long)__float_as_uint(h);
}
__device__ __forceinline__ unsigned long long ld_pair_agent(const unsigned long long* p) {
  return __hip_atomic_load(p, __ATOMIC_RELAXED, __HIP_MEMORY_SCOPE_AGENT);
}
__device__ __forceinline__ void st_pair_agent(unsigned long long* p, unsigned long long v) {
  __hip_atomic_store(p, v, __ATOMIC_RELAXED, __HIP_MEMORY_SCOPE_AGENT);
}
__device__ __forceinline__ unsigned ptag(unsigned long long v) { return (unsigned)(v >> 32); }

// fast activations: v_exp_f32-based, cut the publisher's serial tail from
// ~300-500cy (libm expf/tanhf) to ~60-80cy. sigmoid needs no guard
// (__expf(-x) -> 0 or inf both give correct limits); tanh clamps input so
// e^{2x} stays finite (tanh saturated far below |x|=15 anyway).
__device__ __forceinline__ float fast_sig(float x) {
  return 1.f / (1.f + __expf(-x));
}
__device__ __forceinline__ float fast_tanh(float x) {
  const float xc = fminf(fmaxf(x, -15.f), 15.f);
  const float e  = __expf(2.f * xc);
  return (e - 1.f) / (e + 1.f);
}

// ---------------------------------------------------------------------------
// Persistent bidirectional LSTM, barrier-free across WGs (round-3 protocol,
// single-poll spin — the proven fastest). 64 WGs x 256 threads. Wave w of
// each WG owns k-quarter w of all 64 rows (lane = row): it polls ONLY the
// 128 h-components it consumes (2 tagged pairs per lane). Partial sums
// tree-reduce via parity-double-buffered LDS + one __syncthreads per step;
// wave 0 applies gates and publishes 16 comps as one burst.
// DELTA vs round 11: fast activations on the publish path; no s_sleep in
// the spin (poll loads self-pace at RT cadence).
// ---------------------------------------------------------------------------
__global__ __launch_bounds__(256, 1) void lstm_kernel(
    const float* __restrict__ Whh_f, const float* __restrict__ Whh_b,
    const float* __restrict__ Wih_f, const float* __restrict__ Wih_b,
    const float* __restrict__ b_f,  const float* __restrict__ b_b,
    const float* __restrict__ h0,   const float* __restrict__ c0,
    const int*   __restrict__ x,    const float* __restrict__ embed,
    unsigned long long* __restrict__ pairs,   // [2 dir][2 parity][512]
    float* __restrict__ hOut)                 // [2 dir][T][512]
{
  const int wg   = blockIdx.x;
  const int dir  = wg >> 5;      // 0 fwd, 1 bwd
  const int sl   = wg & 31;
  const int J0   = sl * 16;
  const int tid  = threadIdx.x;
  const int w    = tid >> 6;     // wave 0..3 = k-quarter
  const int l    = tid & 63;     // local row: gate = l>>4, jloc = l&15
  const int jl   = l & 15;
  const int comp = J0 + jl;
  const int grow = (l >> 4) * HID + comp;   // global W row

  const float* Whh = dir ? Whh_b : Whh_f;
  const float* Wih = dir ? Wih_b : Wih_f;
  const float* bb  = dir ? b_b  : b_f;

  // this lane's k-quarter of its row, in registers
  float wh[128];
  {
    const float* wr = Whh + (size_t)grow * HID + w * 128;
    #pragma unroll
    for (int i = 0; i < 32; ++i)
      *(float4*)&wh[i*4] = *(const float4*)&wr[i*4];
  }
  float we[64];
  {
    const float* wr2 = Wih + (size_t)grow * EMB + w * 64;
    #pragma unroll
    for (int i = 0; i < 16; ++i)
      *(float4*)&we[i*4] = *(const float4*)&wr2[i*4];
  }
  const float bi = bb[comp],        bfg = bb[HID + comp];
  const float bg = bb[2*HID + comp], bo = bb[3*HID + comp];
  float c = c0[dir * HID + comp];           // meaningful in wave 0

  __shared__ float hl[4][128];   // per-wave h chunk
  __shared__ float el[4][64];    // per-wave emb quarter
  __shared__ float ps[2][4][64]; // parity-double-buffered partials

  unsigned long long* pb = pairs + (size_t)dir * 2 * 512;

  // publish h_{-1} (parity 1, tag 1); pairs buffer was memset to 0
  if (w == 0 && l < 16)
    st_pair_agent(&pb[512 + J0 + l], packph(h0[dir*HID + J0 + l], 1u));

  // prefetch emb quarter for step 0 (scalar per lane, coalesced per wave)
  float epf;
  {
    const int tt0 = dir ? (T_LEN - 1) : 0;
    epf = embed[(size_t)x[tt0] * EMB + w * 64 + l];
  }

  unsigned spins = 0;

  for (int t = 0; t < T_LEN; ++t) {
    const int par = t & 1;
    const int tt  = dir ? (T_LEN - 1 - t) : t;

    // issue this wave's 2-pair poll early (in flight during emb work)
    unsigned long long* psrc = pb + ((par ^ 1) * 512) + w * 128 + 2 * l;
    unsigned long long sp0 = ld_pair_agent(&psrc[0]);
    unsigned long long sp1 = ld_pair_agent(&psrc[1]);

    // stage emb quarter (intra-wave only: waitcnt + sched fence, no barrier)
    el[w][l] = epf;
    __builtin_amdgcn_wave_barrier();
    asm volatile("s_waitcnt lgkmcnt(0)" ::: "memory");
    __builtin_amdgcn_sched_barrier(0);

    // emb contribution overlaps the poll latency (off the critical path)
    float acc = 0.f;
    {
      const float* eseg = el[w];
      #pragma unroll
      for (int i = 0; i < 16; ++i) {
        float4 ev = *(const float4*)&eseg[i*4];
        acc += we[i*4+0]*ev.x + we[i*4+1]*ev.y + we[i*4+2]*ev.z + we[i*4+3]*ev.w;
      }
    }

    // spin until this wave's 128-word chunk carries tag t+1 (h_{t-1});
    // no sleep: the poll loads self-pace the loop at LLC-RT cadence
    const unsigned tgt = (unsigned)(t + 1);
    for (;;) {
      const bool f = (ptag(sp0) == tgt) && (ptag(sp1) == tgt);
      if (__all(f)) break;
      if (++spins > 6000000u) break;   // safety valve
      sp0 = ld_pair_agent(&psrc[0]);
      sp1 = ld_pair_agent(&psrc[1]);
    }

    // polled chunk -> per-wave LDS
    {
      float2 hv2;
      hv2.x = __uint_as_float((unsigned)sp0);
      hv2.y = __uint_as_float((unsigned)sp1);
      *(float2*)&hl[w][2*l] = hv2;
    }
    __builtin_amdgcn_wave_barrier();
    asm volatile("s_waitcnt lgkmcnt(0)" ::: "memory");
    __builtin_amdgcn_sched_barrier(0);

    // h contribution: 4 independent FMA chains (32 serial FMAs each),
    // combined by a 2-level tree. Same-address LDS reads broadcast.
    {
      const float* hseg = hl[w];
      float a0 = 0.f, a1 = 0.f, a2 = 0.f, a3 = 0.f;
      #pragma unroll
      for (int i = 0; i < 8; ++i) {
        float4 h0v = *(const float4*)&hseg[(4*i+0)*4];
        float4 h1v = *(const float4*)&hseg[(4*i+1)*4];
        float4 h2v = *(const float4*)&hseg[(4*i+2)*4];
        float4 h3v = *(const float4*)&hseg[(4*i+3)*4];
        const float* w0 = &wh[(4*i+0)*4];
        const float* w1 = &wh[(4*i+1)*4];
        const float* w2 = &wh[(4*i+2)*4];
        const float* w3 = &wh[(4*i+3)*4];
        a0 += w0[0]*h0v.x + w0[1]*h0v.y + w0[2]*h0v.z + w0[3]*h0v.w;
        a1 += w1[0]*h1v.x + w1[1]*h1v.y + w1[2]*h1v.z + w1[3]*h1v.w;
        a2 += w2[0]*h2v.x + w2[1]*h2v.y + w2[2]*h2v.z + w2[3]*h2v.w;
        a3 += w3[0]*h3v.x + w3[1]*h3v.y + w3[2]*h3v.z + w3[3]*h3v.w;
      }
      acc += (a0 + a1) + (a2 + a3);
    }

    ps[par][w][l] = acc;
    __syncthreads();   // the one per-step intra-WG join

    if (w == 0) {
      const float q0 = ps[par][0][l], q1 = ps[par][1][l];
      const float q2 = ps[par][2][l], q3 = ps[par][3][l];
      const float tot = (q0 + q1) + (q2 + q3);   // same tree as round 3
      const float g0 = __shfl(tot, jl);          // gate i row
      const float g1 = __shfl(tot, jl + 16);     // gate f
      const float g2 = __shfl(tot, jl + 32);     // gate g
      const float g3 = __shfl(tot, jl + 48);     // gate o
      const float gi_ = g0 + bi, gf_ = g1 + bfg, gg_ = g2 + bg, go_ = g3 + bo;
      const float si = fast_sig(gi_);
      const float sf = fast_sig(gf_);
      const float so = fast_sig(go_);
      const float cn = sf * c + si * fast_tanh(gg_);
      c = cn;
      const float hv = so * fast_tanh(cn);
      if (l < 16) {
        st_pair_agent(&pb[par * 512 + J0 + l], packph(hv, (unsigned)(t + 2)));
        hOut[((size_t)dir * T_LEN + tt) * HID + J0 + l] = hv;
      }
    }

    // prefetch next emb quarter (hides under next step's poll)
    if (t + 1 < T_LEN) {
      const int ttn = dir ? (T_LEN - 2 - t) : (t + 1);
      epf = embed[(size_t)x[ttn] * EMB + w * 64 + l];
    }
  }
}

// ---------------------------------------------------------------------------
// feats[t][k] = concat(hf[t], hb[t]) . fc_w[k] + fc_b[k]
// ---------------------------------------------------------------------------
__global__ __launch_bounds__(256) void feats_kernel(
    const float* __restrict__ hOut, const float* __restrict__ fc_w,
    const float* __restrict__ fc_b, float* __restrict__ feats)
{
  const int tid = threadIdx.x;
  const int k   = tid & 15;
  const int tl  = tid >> 4;
  const int t   = blockIdx.x * 16 + tl;
  const float* hf = hOut + (size_t)t * HID;
  const float* hb = hOut + ((size_t)T_LEN + t) * HID;
  const float* wr = fc_w + (size_t)k * (2 * HID);
  float acc = fc_b[k];
  #pragma unroll 4
  for (int j = 0; j < HID; j += 4) {
    float4 hv = *(const float4*)&hf[j];
    float4 wv = *(const float4*)&wr[j];
    acc += hv.x*wv.x + hv.y*wv.y + hv.z*wv.z + hv.w*wv.w;
  }
  #pragma unroll 4
  for (int j = 0; j < HID; j += 4) {
    float4 hv = *(const float4*)&hb[j];
    float4 wv = *(const float4*)&wr[HID + j];
    acc += hv.x*wv.x + hv.y*wv.y + hv.z*wv.z + hv.w*wv.w;
  }
  feats[(size_t)t * KTAG + k] = acc;
}

// ---------------------------------------------------------------------------
// Viterbi: single block. DP state vl kept in wave-0 REGISTERS (lane 4n holds
// vl[n]); gathers via __shfl — no per-step LDS round trip. First-max tie
// rules preserved exactly. Backtrack via per-64-step chunk maps.
// (Verbatim from rounds 5-7/9/11, all passed.)
// ---------------------------------------------------------------------------
__global__ __launch_bounds__(256) void viterbi_kernel(
    const float* __restrict__ feats, const float* __restrict__ trans,
    float* __restrict__ out)
{
  __shared__ float fch[256 * KTAG];           // 16 KB feats chunk
  __shared__ unsigned char bps8[T_LEN * 8];   // 32 KB packed backpointers
  __shared__ unsigned char ml[64 * 16];       // chunk maps
  __shared__ unsigned char rb[64];            // chunk right-boundary tags
  __shared__ int sbest;

  const int tid  = threadIdx.x;
  const int lane = tid & 63;
  const int nxt  = lane >> 2;
  const int pg   = lane & 3;

  float tr[4] = {0.f, 0.f, 0.f, 0.f};
  if (tid < 64) {
    #pragma unroll
    for (int p = 0; p < 4; ++p)
      tr[p] = trans[nxt * KTAG + pg * 4 + p];
  }
  // vl in registers: lane 4n holds vl[n]
  float vlreg = ((lane >> 2) == START_TAG) ? 0.f : NEGV;
  __syncthreads();

  for (int ch = 0; ch < 16; ++ch) {
    const float* src = feats + (size_t)ch * 256 * KTAG;
    #pragma unroll
    for (int i = 0; i < 4; ++i)
      *(float4*)&fch[(i * 256 + tid) * 4] = *(const float4*)&src[(i * 256 + tid) * 4];
    __syncthreads();

    if (tid < 64) {
      const int sbase = pg << 4;
      for (int tl = 0; tl < 256; ++tl) {
        const int t = ch * 256 + tl;
        const float s0 = __shfl(vlreg, sbase);
        const float s1 = __shfl(vlreg, sbase + 4);
        const float s2 = __shfl(vlreg, sbase + 8);
        const float s3 = __shfl(vlreg, sbase + 12);
        float best = s0 + tr[0]; int bp = pg * 4;
        float sc = s1 + tr[1]; if (sc > best) { best = sc; bp = pg * 4 + 1; }
        sc = s2 + tr[2]; if (sc > best) { best = sc; bp = pg * 4 + 2; }
        sc = s3 + tr[3]; if (sc > best) { best = sc; bp = pg * 4 + 3; }
        #pragma unroll
        for (int m = 1; m <= 2; m <<= 1) {      // merge groups, prefer lower idx
          const float ob = __shfl_xor(best, m);
          const int  obp = __shfl_xor(bp, m);
          if (ob > best || (ob == best && obp < bp)) { best = ob; bp = obp; }
        }
        const int nbp = __shfl(bp, (lane + 4) & 63);  // neighbor next's bp
        if (pg == 0 && (nxt & 1) == 0)
          bps8[t * 8 + (nxt >> 1)] = (unsigned char)(bp | (nbp << 4));
        const float fv = fch[tl * KTAG + nxt];
        vlreg = (pg == 0) ? (best + fv) : vlreg;
      }
    }
    __syncthreads();
  }

  if (tid < 64) {
    const float vfin = __shfl(vlreg, (lane & 15) << 2);
    float term = (lane < KTAG) ? (vfin + trans[END_TAG * KTAG + lane]) : -3.0e38f;
    int bt = (lane < KTAG) ? lane : KTAG;
    #pragma unroll
    for (int m = 1; m < 64; m <<= 1) {
      const float ot = __shfl_xor(term, m);
      const int  obt = __shfl_xor(bt, m);
      if (ot > term || (ot == term && obt < bt)) { term = ot; bt = obt; }
    }
    if (lane == 0) { out[0] = term; sbest = bt; }
  }
  __syncthreads();

  if (tid < 64) {
    const int L = lane;
    unsigned char cur[16];
    #pragma unroll
    for (int g = 0; g < 16; ++g) cur[g] = (unsigned char)g;
    for (int i = 63; i >= 0; --i) {
      const int t = L * 64 + i;
      #pragma unroll
      for (int g = 0; g < 16; ++g) {
        const unsigned char cc = cur[g];
        const unsigned char by = bps8[t * 8 + (cc >> 1)];
        cur[g] = (cc & 1) ? (by >> 4) : (by & 15);
      }
    }
    #pragma unroll
    for (int g = 0; g < 16; ++g) ml[L * 16 + g] = cur[g];
  }
  __syncthreads();

  if (tid == 0) {
    int r = sbest;
    rb[63] = (unsigned char)r;
    for (int cix = 62; cix >= 0; --cix) {
      r = ml[(cix + 1) * 16 + r];
      rb[cix] = (unsigned char)r;
    }
  }
  __syncthreads();

  if (tid < 64) {
    const int L = lane;
    int tag = rb[L];
    out[1 + L * 64 + 63] = (float)tag;
    for (int i = 62; i >= 0; --i) {
      const int t = L * 64 + i + 1;
      const unsigned char by = bps8[t * 8 + (tag >> 1)];
      tag = (tag & 1) ? (by >> 4) : (by & 15);
      out[1 + L * 64 + i] = (float)tag;
    }
  }
}

// ---------------------------------------------------------------------------
extern "C" void kernel_launch(void* const* d_in, const int* in_sizes, int n_in,
                              void* d_out, int out_size, void* d_ws, size_t ws_size,
                              hipStream_t stream) {
  (void)in_sizes; (void)n_in; (void)out_size; (void)ws_size;
  const int*   x      = (const int*)  d_in[0];
  const float* h0     = (const float*)d_in[1];
  const float* c0     = (const float*)d_in[2];
  const float* embed  = (const float*)d_in[3];
  const float* Wih_f  = (const float*)d_in[4];
  const float* Whh_f  = (const float*)d_in[5];
  const float* b_f    = (const float*)d_in[6];
  const float* Wih_b  = (const float*)d_in[7];
  const float* Whh_b  = (const float*)d_in[8];
  const float* b_b    = (const float*)d_in[9];
  const float* fc_w   = (const float*)d_in[10];
  const float* fc_b   = (const float*)d_in[11];
  const float* trans  = (const float*)d_in[12];
  float* out = (float*)d_out;

  char* ws = (char*)d_ws;
  unsigned long long* pairs = (unsigned long long*)(ws + 0);  // 16 KB
  float* feats    = (float*)(ws + 65536);                     // 256 KB
  float* hOut     = (float*)(ws + (1ull << 20));              // 16 MB

  // zero all tags so stale/poison data can never satisfy a poll
  hipMemsetAsync(pairs, 0, 2 * 2 * 512 * sizeof(unsigned long long), stream);

  {
    void* args[] = {
      (void*)&Whh_f, (void*)&Whh_b, (void*)&Wih_f, (void*)&Wih_b,
      (void*)&b_f,   (void*)&b_b,   (void*)&h0,    (void*)&c0,
      (void*)&x,     (void*)&embed, (void*)&pairs, (void*)&hOut
    };
    hipLaunchCooperativeKernel((const void*)lstm_kernel, dim3(NWG), dim3(256),
                               args, 0, stream);
  }

  feats_kernel<<<dim3(T_LEN / 16), 256, 0, stream>>>(hOut, fc_w, fc_b, feats);
  viterbi_kernel<<<dim3(1), 256, 0, stream>>>(feats, trans, out);
}

// Round 13
// 8475.311 us; speedup vs baseline: 4.4576x; 1.1441x over previous
//
#include <hip/hip_runtime.h>
#include <hip/hip_bf16.h>

#define T_LEN 4096
#define HID   512
#define EMB   256
#define KTAG  16
#define START_TAG 14
#define END_TAG   15
#define NEGV  (-10000.0f)
#define NWG   64   // 32 workgroups per direction (round-3 structure)

__device__ __forceinline__ unsigned long long packph(float h, unsigned tag) {
  return ((unsigned long long)tag << 32) | (unsigned long long)__float_as_uint(h);
}
__device__ __forceinline__ unsigned long long ld_pair_agent(const unsigned long long* p) {
  return __hip_atomic_load(p, __ATOMIC_RELAXED, __HIP_MEMORY_SCOPE_AGENT);
}
__device__ __forceinline__ void st_pair_agent(unsigned long long* p, unsigned long long v) {
  __hip_atomic_store(p, v, __ATOMIC_RELAXED, __HIP_MEMORY_SCOPE_AGENT);
}
__device__ __forceinline__ unsigned ptag(unsigned long long v) { return (unsigned)(v >> 32); }

// fast activations (proven round 12)
__device__ __forceinline__ float fast_sig(float x) {
  return 1.f / (1.f + __expf(-x));
}
__device__ __forceinline__ float fast_tanh(float x) {
  const float xc = fminf(fmaxf(x, -15.f), 15.f);
  const float e  = __expf(2.f * xc);
  return (e - 1.f) / (e + 1.f);
}

// ---------------------------------------------------------------------------
// Persistent bidirectional LSTM — VERBATIM round 12 (proven 8.6 ms).
// ---------------------------------------------------------------------------
__global__ __launch_bounds__(256, 1) void lstm_kernel(
    const float* __restrict__ Whh_f, const float* __restrict__ Whh_b,
    const float* __restrict__ Wih_f, const float* __restrict__ Wih_b,
    const float* __restrict__ b_f,  const float* __restrict__ b_b,
    const float* __restrict__ h0,   const float* __restrict__ c0,
    const int*   __restrict__ x,    const float* __restrict__ embed,
    unsigned long long* __restrict__ pairs,   // [2 dir][2 parity][512]
    float* __restrict__ hOut)                 // [2 dir][T][512]
{
  const int wg   = blockIdx.x;
  const int dir  = wg >> 5;      // 0 fwd, 1 bwd
  const int sl   = wg & 31;
  const int J0   = sl * 16;
  const int tid  = threadIdx.x;
  const int w    = tid >> 6;     // wave 0..3 = k-quarter
  const int l    = tid & 63;     // local row: gate = l>>4, jloc = l&15
  const int jl   = l & 15;
  const int comp = J0 + jl;
  const int grow = (l >> 4) * HID + comp;   // global W row

  const float* Whh = dir ? Whh_b : Whh_f;
  const float* Wih = dir ? Wih_b : Wih_f;
  const float* bb  = dir ? b_b  : b_f;

  float wh[128];
  {
    const float* wr = Whh + (size_t)grow * HID + w * 128;
    #pragma unroll
    for (int i = 0; i < 32; ++i)
      *(float4*)&wh[i*4] = *(const float4*)&wr[i*4];
  }
  float we[64];
  {
    const float* wr2 = Wih + (size_t)grow * EMB + w * 64;
    #pragma unroll
    for (int i = 0; i < 16; ++i)
      *(float4*)&we[i*4] = *(const float4*)&wr2[i*4];
  }
  const float bi = bb[comp],        bfg = bb[HID + comp];
  const float bg = bb[2*HID + comp], bo = bb[3*HID + comp];
  float c = c0[dir * HID + comp];           // meaningful in wave 0

  __shared__ float hl[4][128];   // per-wave h chunk
  __shared__ float el[4][64];    // per-wave emb quarter
  __shared__ float ps[2][4][64]; // parity-double-buffered partials

  unsigned long long* pb = pairs + (size_t)dir * 2 * 512;

  if (w == 0 && l < 16)
    st_pair_agent(&pb[512 + J0 + l], packph(h0[dir*HID + J0 + l], 1u));

  float epf;
  {
    const int tt0 = dir ? (T_LEN - 1) : 0;
    epf = embed[(size_t)x[tt0] * EMB + w * 64 + l];
  }

  unsigned spins = 0;

  for (int t = 0; t < T_LEN; ++t) {
    const int par = t & 1;
    const int tt  = dir ? (T_LEN - 1 - t) : t;

    unsigned long long* psrc = pb + ((par ^ 1) * 512) + w * 128 + 2 * l;
    unsigned long long sp0 = ld_pair_agent(&psrc[0]);
    unsigned long long sp1 = ld_pair_agent(&psrc[1]);

    el[w][l] = epf;
    __builtin_amdgcn_wave_barrier();
    asm volatile("s_waitcnt lgkmcnt(0)" ::: "memory");
    __builtin_amdgcn_sched_barrier(0);

    float acc = 0.f;
    {
      const float* eseg = el[w];
      #pragma unroll
      for (int i = 0; i < 16; ++i) {
        float4 ev = *(const float4*)&eseg[i*4];
        acc += we[i*4+0]*ev.x + we[i*4+1]*ev.y + we[i*4+2]*ev.z + we[i*4+3]*ev.w;
      }
    }

    const unsigned tgt = (unsigned)(t + 1);
    for (;;) {
      const bool f = (ptag(sp0) == tgt) && (ptag(sp1) == tgt);
      if (__all(f)) break;
      if (++spins > 6000000u) break;   // safety valve
      sp0 = ld_pair_agent(&psrc[0]);
      sp1 = ld_pair_agent(&psrc[1]);
    }

    {
      float2 hv2;
      hv2.x = __uint_as_float((unsigned)sp0);
      hv2.y = __uint_as_float((unsigned)sp1);
      *(float2*)&hl[w][2*l] = hv2;
    }
    __builtin_amdgcn_wave_barrier();
    asm volatile("s_waitcnt lgkmcnt(0)" ::: "memory");
    __builtin_amdgcn_sched_barrier(0);

    {
      const float* hseg = hl[w];
      float a0 = 0.f, a1 = 0.f, a2 = 0.f, a3 = 0.f;
      #pragma unroll
      for (int i = 0; i < 8; ++i) {
        float4 h0v = *(const float4*)&hseg[(4*i+0)*4];
        float4 h1v = *(const float4*)&hseg[(4*i+1)*4];
        float4 h2v = *(const float4*)&hseg[(4*i+2)*4];
        float4 h3v = *(const float4*)&hseg[(4*i+3)*4];
        const float* w0 = &wh[(4*i+0)*4];
        const float* w1 = &wh[(4*i+1)*4];
        const float* w2 = &wh[(4*i+2)*4];
        const float* w3 = &wh[(4*i+3)*4];
        a0 += w0[0]*h0v.x + w0[1]*h0v.y + w0[2]*h0v.z + w0[3]*h0v.w;
        a1 += w1[0]*h1v.x + w1[1]*h1v.y + w1[2]*h1v.z + w1[3]*h1v.w;
        a2 += w2[0]*h2v.x + w2[1]*h2v.y + w2[2]*h2v.z + w2[3]*h2v.w;
        a3 += w3[0]*h3v.x + w3[1]*h3v.y + w3[2]*h3v.z + w3[3]*h3v.w;
      }
      acc += (a0 + a1) + (a2 + a3);
    }

    ps[par][w][l] = acc;
    __syncthreads();   // the one per-step intra-WG join

    if (w == 0) {
      const float q0 = ps[par][0][l], q1 = ps[par][1][l];
      const float q2 = ps[par][2][l], q3 = ps[par][3][l];
      const float tot = (q0 + q1) + (q2 + q3);
      const float g0 = __shfl(tot, jl);          // gate i row
      const float g1 = __shfl(tot, jl + 16);     // gate f
      const float g2 = __shfl(tot, jl + 32);     // gate g
      const float g3 = __shfl(tot, jl + 48);     // gate o
      const float gi_ = g0 + bi, gf_ = g1 + bfg, gg_ = g2 + bg, go_ = g3 + bo;
      const float si = fast_sig(gi_);
      const float sf = fast_sig(gf_);
      const float so = fast_sig(go_);
      const float cn = sf * c + si * fast_tanh(gg_);
      c = cn;
      const float hv = so * fast_tanh(cn);
      if (l < 16) {
        st_pair_agent(&pb[par * 512 + J0 + l], packph(hv, (unsigned)(t + 2)));
        hOut[((size_t)dir * T_LEN + tt) * HID + J0 + l] = hv;
      }
    }

    if (t + 1 < T_LEN) {
      const int ttn = dir ? (T_LEN - 2 - t) : (t + 1);
      epf = embed[(size_t)x[ttn] * EMB + w * 64 + l];
    }
  }
}

// ---------------------------------------------------------------------------
// feats — VERBATIM round 12.
// ---------------------------------------------------------------------------
__global__ __launch_bounds__(256) void feats_kernel(
    const float* __restrict__ hOut, const float* __restrict__ fc_w,
    const float* __restrict__ fc_b, float* __restrict__ feats)
{
  const int tid = threadIdx.x;
  const int k   = tid & 15;
  const int tl  = tid >> 4;
  const int t   = blockIdx.x * 16 + tl;
  const float* hf = hOut + (size_t)t * HID;
  const float* hb = hOut + ((size_t)T_LEN + t) * HID;
  const float* wr = fc_w + (size_t)k * (2 * HID);
  float acc = fc_b[k];
  #pragma unroll 4
  for (int j = 0; j < HID; j += 4) {
    float4 hv = *(const float4*)&hf[j];
    float4 wv = *(const float4*)&wr[j];
    acc += hv.x*wv.x + hv.y*wv.y + hv.z*wv.z + hv.w*wv.w;
  }
  #pragma unroll 4
  for (int j = 0; j < HID; j += 4) {
    float4 hv = *(const float4*)&hb[j];
    float4 wv = *(const float4*)&wr[HID + j];
    acc += hv.x*wv.x + hv.y*wv.y + hv.z*wv.z + hv.w*wv.w;
  }
  feats[(size_t)t * KTAG + k] = acc;
}

// ===========================================================================
// Parallel Viterbi (max-plus scan), 4 plain kernels.
// M_t[n][p] = trans[n][p] + feat[t][n];  vl'[n] = max_p(vl[p] + M_t[n][p]).
// ===========================================================================

// K1: chunk products. WG c builds P_c = M_{c64+63} o ... o M_{c64} (16x16).
// LDS holds PT[j][k] = P[k][j] so each update reads contiguous rows.
__global__ __launch_bounds__(64) void vit_prod(
    const float* __restrict__ feats, const float* __restrict__ trans,
    float* __restrict__ Pg)   // [64][16][16] row-major P[c][n][k]
{
  const int c  = blockIdx.x;
  const int l  = threadIdx.x;
  const int n  = l >> 2;
  const int pg = l & 3;
  const int t0 = c * 64;

  float tr[16];
  #pragma unroll
  for (int k = 0; k < 16; ++k) tr[k] = trans[n * 16 + k];

  __shared__ float PT[2][16][16];   // PT[buf][j][k] = P[k][j]

  // init: P0[n][j] = trans[n][j] + f0[n]  ->  PT[j][n]
  {
    const float f0 = feats[t0 * 16 + n];
    #pragma unroll
    for (int q = 0; q < 4; ++q)
      PT[0][4 * pg + q][n] = tr[4 * pg + q] + f0;
  }
  __syncthreads();

  int cur = 0;
  for (int i = 1; i < 64; ++i) {
    const float fn = feats[(t0 + i) * 16 + n];
    // P'[n][j] = fn + max_k(tr[k] + P[k][j]);  P[k][j] = PT[cur][j][k]
    #pragma unroll
    for (int q = 0; q < 4; ++q) {
      const int j = 4 * pg + q;
      const float* row = PT[cur][j];
      float m = tr[0] + row[0];
      #pragma unroll
      for (int k = 1; k < 16; ++k) m = fmaxf(m, tr[k] + row[k]);
      PT[cur ^ 1][j][n] = fn + m;
    }
    __syncthreads();
    cur ^= 1;
  }

  // write out in normal layout: Pg[c][n][k] = PT[cur][k][n]
  {
    float4 v;
    v.x = PT[cur][4 * pg + 0][n];
    v.y = PT[cur][4 * pg + 1][n];
    v.z = PT[cur][4 * pg + 2][n];
    v.w = PT[cur][4 * pg + 3][n];
    *(float4*)&Pg[(size_t)c * 256 + n * 16 + 4 * pg] = v;
  }
}

// K2: exclusive scan over chunk products -> vstart[c][16].
__global__ __launch_bounds__(64) void vit_scan(
    const float* __restrict__ Pg, float* __restrict__ vstart)
{
  const int l  = threadIdx.x;
  const int n  = l >> 2;
  const int pg = l & 3;

  float v4[4];   // v[4pg+p], replicated across n
  #pragma unroll
  for (int p = 0; p < 4; ++p) v4[p] = (4 * pg + p == START_TAG) ? 0.f : NEGV;

  float4 P4 = *(const float4*)&Pg[(size_t)0 * 256 + n * 16 + 4 * pg];

  for (int c = 0; c < 64; ++c) {
    // exclusive: store v at chunk entry (lanes n==0 cover all 16)
    if (n == 0)
      *(float4*)&vstart[c * 16 + 4 * pg] = *(float4*)v4;

    // prefetch next chunk's row-quarter
    float4 Pn;
    if (c + 1 < 64)
      Pn = *(const float4*)&Pg[(size_t)(c + 1) * 256 + n * 16 + 4 * pg];

    // v'[n] = max_k(P_c[n][k] + v[k]) : this lane's k-quarter partial
    float part = P4.x + v4[0];
    part = fmaxf(part, P4.y + v4[1]);
    part = fmaxf(part, P4.z + v4[2]);
    part = fmaxf(part, P4.w + v4[3]);
    // merge across the 4 pg lanes of group n
    part = fmaxf(part, __shfl_xor(part, 1));
    part = fmaxf(part, __shfl_xor(part, 2));
    // redistribute: v4'[p] = v'[4pg+p] from lane (4pg+p)*4
    #pragma unroll
    for (int p = 0; p < 4; ++p)
      v4[p] = __shfl(part, (4 * pg + p) << 2);

    P4 = Pn;
  }
}

// K3: per-chunk serial recompute (r12-verbatim inner loop) from exact
// chunk-entry vector; emits backpointers + chunk map; chunk 63 emits score.
__global__ __launch_bounds__(64) void vit_rec(
    const float* __restrict__ feats, const float* __restrict__ trans,
    const float* __restrict__ vstart,
    unsigned long long* __restrict__ bpsg,   // [64][64] u64 (=[T][8] bytes)
    unsigned char* __restrict__ gmaps,       // [64][16]
    int* __restrict__ sbest_g, float* __restrict__ out)
{
  const int c    = blockIdx.x;
  const int lane = threadIdx.x;
  const int nxt  = lane >> 2;
  const int pg   = lane & 3;

  __shared__ float fch[64 * KTAG];          // 4 KB feats chunk
  __shared__ unsigned char bps8[64 * 8];    // 512 B packed backpointers

  // stage this chunk's feats: thread i loads row i (16 floats)
  {
    const float* src = feats + (size_t)c * 64 * KTAG + lane * KTAG;
    #pragma unroll
    for (int i = 0; i < 4; ++i)
      *(float4*)&fch[lane * KTAG + i * 4] = *(const float4*)&src[i * 4];
  }

  float tr[4];
  #pragma unroll
  for (int p = 0; p < 4; ++p)
    tr[p] = trans[nxt * KTAG + pg * 4 + p];

  float vlreg = vstart[c * 16 + (lane >> 2)];   // lane 4n holds vl[n] (replicated)
  __syncthreads();

  {
    const int sbase = pg << 4;
    for (int tl2 = 0; tl2 < 64; ++tl2) {
      const float s0 = __shfl(vlreg, sbase);
      const float s1 = __shfl(vlreg, sbase + 4);
      const float s2 = __shfl(vlreg, sbase + 8);
      const float s3 = __shfl(vlreg, sbase + 12);
      float best = s0 + tr[0]; int bp = pg * 4;
      float sc = s1 + tr[1]; if (sc > best) { best = sc; bp = pg * 4 + 1; }
      sc = s2 + tr[2]; if (sc > best) { best = sc; bp = pg * 4 + 2; }
      sc = s3 + tr[3]; if (sc > best) { best = sc; bp = pg * 4 + 3; }
      #pragma unroll
      for (int m = 1; m <= 2; m <<= 1) {      // merge groups, prefer lower idx
        const float ob = __shfl_xor(best, m);
        const int  obp = __shfl_xor(bp, m);
        if (ob > best || (ob == best && obp < bp)) { best = ob; bp = obp; }
      }
      const int nbp = __shfl(bp, (lane + 4) & 63);  // neighbor next's bp
      if (pg == 0 && (nxt & 1) == 0)
        bps8[tl2 * 8 + (nxt >> 1)] = (unsigned char)(bp | (nbp << 4));
      const float fv = fch[tl2 * KTAG + nxt];
      vlreg = (pg == 0) ? (best + fv) : vlreg;
    }
  }
  __syncthreads();

  // chunk 63: terminal score + argmax (r12 verbatim)
  if (c == 63) {
    const float vfin = __shfl(vlreg, (lane & 15) << 2);
    float term = (lane < KTAG) ? (vfin + trans[END_TAG * KTAG + lane]) : -3.0e38f;
    int bt = (lane < KTAG) ? lane : KTAG;
    #pragma unroll
    for (int m = 1; m < 64; m <<= 1) {
      const float ot = __shfl_xor(term, m);
      const int  obt = __shfl_xor(bt, m);
      if (ot > term || (ot == term && obt < bt)) { term = ot; bt = obt; }
    }
    if (lane == 0) { out[0] = term; *sbest_g = bt; }
  }

  // chunk map: lane g composes exit-tag g -> entry tag
  if (lane < 16) {
    int cc = lane;
    for (int i = 63; i >= 0; --i) {
      const unsigned char by = bps8[i * 8 + (cc >> 1)];
      cc = (cc & 1) ? (by >> 4) : (by & 15);
    }
    gmaps[c * 16 + lane] = (unsigned char)cc;
  }

  // dump backpointers
  bpsg[(size_t)c * 64 + lane] = ((const unsigned long long*)bps8)[lane];
}

// K4: boundary resolution + path fill (r12 backtrack, LDS-staged).
__global__ __launch_bounds__(256) void vit_back(
    const unsigned long long* __restrict__ bpsg,
    const unsigned char* __restrict__ gmaps,
    const int* __restrict__ sbest_g, float* __restrict__ out)
{
  __shared__ unsigned char bps8[T_LEN * 8];   // 32 KB
  __shared__ unsigned char ml[64 * 16];
  __shared__ unsigned char rb[64];

  const int tid = threadIdx.x;

  {
    unsigned long long* d = (unsigned long long*)bps8;
    #pragma unroll
    for (int i = 0; i < 16; ++i)
      d[tid * 16 + i] = bpsg[tid * 16 + i];
  }
  if (tid < 64) {
    #pragma unroll
    for (int g = 0; g < 16; ++g)
      ml[tid * 16 + g] = gmaps[tid * 16 + g];
  }
  __syncthreads();

  if (tid == 0) {
    int r = *sbest_g;
    rb[63] = (unsigned char)r;
    for (int cix = 62; cix >= 0; --cix) {
      r = ml[(cix + 1) * 16 + r];
      rb[cix] = (unsigned char)r;
    }
  }
  __syncthreads();

  if (tid < 64) {
    const int L = tid;
    int tag = rb[L];
    out[1 + L * 64 + 63] = (float)tag;
    for (int i = 62; i >= 0; --i) {
      const int t = L * 64 + i + 1;
      const unsigned char by = bps8[t * 8 + (tag >> 1)];
      tag = (tag & 1) ? (by >> 4) : (by & 15);
      out[1 + L * 64 + i] = (float)tag;
    }
  }
}

// ---------------------------------------------------------------------------
extern "C" void kernel_launch(void* const* d_in, const int* in_sizes, int n_in,
                              void* d_out, int out_size, void* d_ws, size_t ws_size,
                              hipStream_t stream) {
  (void)in_sizes; (void)n_in; (void)out_size; (void)ws_size;
  const int*   x      = (const int*)  d_in[0];
  const float* h0     = (const float*)d_in[1];
  const float* c0     = (const float*)d_in[2];
  const float* embed  = (const float*)d_in[3];
  const float* Wih_f  = (const float*)d_in[4];
  const float* Whh_f  = (const float*)d_in[5];
  const float* b_f    = (const float*)d_in[6];
  const float* Wih_b  = (const float*)d_in[7];
  const float* Whh_b  = (const float*)d_in[8];
  const float* b_b    = (const float*)d_in[9];
  const float* fc_w   = (const float*)d_in[10];
  const float* fc_b   = (const float*)d_in[11];
  const float* trans  = (const float*)d_in[12];
  float* out = (float*)d_out;

  char* ws = (char*)d_ws;
  unsigned long long* pairs  = (unsigned long long*)(ws + 0);        // 16 KB
  float* feats               = (float*)(ws + 65536);                 // 256 KB
  float* Pg                  = (float*)(ws + 327680);                // 64 KB
  float* vstart              = (float*)(ws + 393216);                // 4 KB
  unsigned char* gmaps       = (unsigned char*)(ws + 397312);        // 1 KB
  int* sbest_g               = (int*)(ws + 398336);                  // 4 B
  unsigned long long* bpsg   = (unsigned long long*)(ws + 399360);   // 32 KB
  float* hOut                = (float*)(ws + (1ull << 20));          // 16 MB

  // zero pair tags so stale/poison data can never satisfy a poll
  hipMemsetAsync(pairs, 0, 2 * 2 * 512 * sizeof(unsigned long long), stream);

  {
    void* args[] = {
      (void*)&Whh_f, (void*)&Whh_b, (void*)&Wih_f, (void*)&Wih_b,
      (void*)&b_f,   (void*)&b_b,   (void*)&h0,    (void*)&c0,
      (void*)&x,     (void*)&embed, (void*)&pairs, (void*)&hOut
    };
    hipLaunchCooperativeKernel((const void*)lstm_kernel, dim3(NWG), dim3(256),
                               args, 0, stream);
  }

  feats_kernel<<<dim3(T_LEN / 16), 256, 0, stream>>>(hOut, fc_w, fc_b, feats);
  vit_prod<<<dim3(64), 64, 0, stream>>>(feats, trans, Pg);
  vit_scan<<<dim3(1), 64, 0, stream>>>(Pg, vstart);
  vit_rec <<<dim3(64), 64, 0, stream>>>(feats, trans, vstart, bpsg, gmaps,
                                        sbest_g, out);
  vit_back<<<dim3(1), 256, 0, stream>>>(bpsg, gmaps, sbest_g, out);
}